// Round 3
// baseline (3199.400 us; speedup 1.0000x reference)
//
#include <hip/hip_runtime.h>
#include <hip/hip_bf16.h>

#define NPAT 50000
#define NCON 20000
#define NN   70000
#define EE   800000
#define H    128

#define NCON_AL  20032                 // concepts padded to 64-alignment
#define SEGN     (NCON_AL + NPAT)      // 70032 segment ids
#define NBUCK    1095                  // ceil(SEGN/64)
#define SEGN_PAD (NBUCK * 64)          // 70080
#define RELSPLIT_B 313                 // buckets [0,313) = concepts (rel0)

__device__ inline unsigned short f2bf(float f) {
    unsigned u = __float_as_uint(f);
    unsigned r = (u + 0x7FFFu + ((u >> 16) & 1u)) >> 16;
    return (unsigned short)r;
}

// ============ seg histogram (counts for mean + bucket sizing) ============
__global__ void hist_kernel(const int* __restrict__ dst_pc, const int* __restrict__ dst_cp,
                            int* __restrict__ deg) {
    int i = blockIdx.x * blockDim.x + threadIdx.x;
    if (i < EE) atomicAdd(&deg[dst_pc[i]], 1);
    else if (i < 2 * EE) atomicAdd(&deg[NCON_AL + dst_cp[i - EE]], 1);
}

// ============ bucket offsets: one block; thread t sums buckets 2t,2t+1 ============
__global__ __launch_bounds__(1024) void bucket_scan_kernel(const int* __restrict__ deg,
                                                           int* __restrict__ boff,
                                                           int* __restrict__ bcur) {
    int t = threadIdx.x;
    int s0 = 0, s1 = 0;
    if (2 * t < NBUCK) {
        const int4* p = (const int4*)&deg[2 * t * 64];
#pragma unroll
        for (int j = 0; j < 16; j++) { int4 v = p[j]; s0 += v.x + v.y + v.z + v.w; }
    }
    if (2 * t + 1 < NBUCK) {
        const int4* p = (const int4*)&deg[(2 * t + 1) * 64];
#pragma unroll
        for (int j = 0; j < 16; j++) { int4 v = p[j]; s1 += v.x + v.y + v.z + v.w; }
    }
    int s = s0 + s1;
    __shared__ int sm[1024];
    sm[t] = s;
    __syncthreads();
    for (int o = 1; o < 1024; o <<= 1) {
        int v = (t >= o) ? sm[t - o] : 0;
        __syncthreads();
        sm[t] += v;
        __syncthreads();
    }
    int pref = sm[t] - s;  // exclusive
    if (2 * t < NBUCK)     { boff[2 * t] = pref;          bcur[2 * t] = pref; }
    if (2 * t + 1 < NBUCK) { boff[2 * t + 1] = pref + s0; bcur[2 * t + 1] = pref + s0; }
    if (t == 1023) boff[NBUCK] = sm[1023];
}

// ============ binning: append packed (src | dl<<16) per bucket ============
__global__ void binpack_kernel(const int* __restrict__ dst_pc, const int* __restrict__ src_pc,
                               const int* __restrict__ dst_cp, const int* __restrict__ src_cp,
                               int* __restrict__ bcur, unsigned* __restrict__ pairs) {
    int i = blockIdx.x * blockDim.x + threadIdx.x;
    int seg, src;
    if (i < EE)           { seg = dst_pc[i];              src = src_pc[i]; }
    else if (i < 2 * EE)  { seg = NCON_AL + dst_cp[i - EE]; src = src_cp[i - EE]; }
    else return;
    int b = seg >> 6;
    int pos = atomicAdd(&bcur[b], 1);
    pairs[pos] = (unsigned)src | ((unsigned)(seg & 63) << 16);
}

// ============ mean aggregation: one block per bucket, LDS accumulator ============
// gathers bf16 rows (256B/edge), accumulates fp32 in LDS via atomics, writes bf16 aggn
__global__ __launch_bounds__(256) void aggregate_kernel(
        const unsigned short* __restrict__ xbf, const unsigned* __restrict__ pairs,
        const int* __restrict__ boff, const int* __restrict__ deg,
        unsigned short* __restrict__ aggn) {
    __shared__ float acc[64][H];  // 32 KB
    int tid = threadIdx.x;
    float4 z4 = make_float4(0.f, 0.f, 0.f, 0.f);
#pragma unroll
    for (int i = 0; i < 8; i++) *(float4*)&((float*)acc)[(i * 256 + tid) * 4] = z4;
    __syncthreads();

    int b = blockIdx.x;
    int ebeg = boff[b], eend = boff[b + 1];
    int rowbase = (b < RELSPLIT_B) ? 0 : NPAT;  // rel0 srcs = patients, rel1 = concepts
    int lane = tid & 63, wid = tid >> 6;
    int sw = lane >> 5;  // bank-conflict swap: lanes 32-63 write (odd,even) order

    for (int e0 = ebeg + wid * 64; e0 < eend; e0 += 256) {
        int ne = min(64, eend - e0);
        unsigned pk = (lane < ne) ? pairs[e0 + lane] : 0u;
        if (ne == 64) {
#pragma unroll 4
            for (int j = 0; j < 64; j++) {
                unsigned pj = __shfl(pk, j);
                int src = pj & 0xFFFF;
                int dl  = pj >> 16;
                unsigned v = *(const unsigned*)&xbf[(size_t)(rowbase + src) * H + 2 * lane];
                float vx = __uint_as_float(v << 16);
                float vy = __uint_as_float(v & 0xFFFF0000u);
                float* row = acc[dl];
                atomicAdd(&row[2 * lane + sw],     sw ? vy : vx);
                atomicAdd(&row[2 * lane + 1 - sw], sw ? vx : vy);
            }
        } else {
            for (int j = 0; j < ne; j++) {
                unsigned pj = __shfl(pk, j);
                int src = pj & 0xFFFF;
                int dl  = pj >> 16;
                unsigned v = *(const unsigned*)&xbf[(size_t)(rowbase + src) * H + 2 * lane];
                float vx = __uint_as_float(v << 16);
                float vy = __uint_as_float(v & 0xFFFF0000u);
                float* row = acc[dl];
                atomicAdd(&row[2 * lane + sw],     sw ? vy : vx);
                atomicAdd(&row[2 * lane + 1 - sw], sw ? vx : vy);
            }
        }
    }
    __syncthreads();

    // write out: thread -> row r = tid>>2, 32 cols at (tid&3)*32; mean + bf16
    int r = tid >> 2, cb = (tid & 3) * 32;
    int seg = b * 64 + r;
    int seglim = (b < RELSPLIT_B) ? NCON : SEGN;
    if (seg < seglim) {
        float inv = 1.0f / (float)max(deg[seg], 1);
#pragma unroll
        for (int q = 0; q < 8; q++) {
            float4 f = *(float4*)&acc[r][cb + q * 4];
            ushort4 o;
            o.x = f2bf(f.x * inv); o.y = f2bf(f.y * inv);
            o.z = f2bf(f.z * inv); o.w = f2bf(f.w * inv);
            *(ushort4*)&aggn[(size_t)seg * H + cb + q * 4] = o;
        }
    }
}

// ============ fused fp32 GEMM: C = [A1(fp32) | A2(bf16)] @ [B1;B2] + bias ============
#define BM 128
#define BK 8

struct GemmJob {
    const float* A1; const unsigned short* A2bf;   // A2 lda == H
    const float* B1; const float* B2;              // [K1,128],[K2,128] fp32
    const float* bias; float* C; unsigned short* Cbf;
    int lda1, K1, K2, M, relu;
};

__global__ void gemm_dual_kernel(GemmJob j0, GemmJob j1, int nb0) {
    __shared__ float sA[BK][BM];
    __shared__ float sB[BK][H];
    bool first = (int)blockIdx.x < nb0;
    GemmJob j = first ? j0 : j1;
    int bm = (first ? blockIdx.x : blockIdx.x - nb0) * BM;
    int tid = threadIdx.x;
    int am = tid >> 1;
    int ak = (tid & 1) * 4;
    int bk = tid >> 5;
    int bn = (tid & 31) * 4;
    int ty = tid >> 4;
    int tx = tid & 15;
    float acc[8][8] = {};
    int Ktot = j.K1 + j.K2;
    for (int k0 = 0; k0 < Ktot; k0 += BK) {
        int gm = bm + am; if (gm >= j.M) gm = j.M - 1;
        float4 av;
        const float* Bs;
        if (k0 < j.K1) {
            av = *(const float4*)&j.A1[(size_t)gm * j.lda1 + k0 + ak];
            Bs = j.B1 + (size_t)k0 * H;
        } else {
            int kk = k0 - j.K1;
            ushort4 uv = *(const ushort4*)&j.A2bf[(size_t)gm * H + kk + ak];
            av.x = __uint_as_float((unsigned)uv.x << 16);
            av.y = __uint_as_float((unsigned)uv.y << 16);
            av.z = __uint_as_float((unsigned)uv.z << 16);
            av.w = __uint_as_float((unsigned)uv.w << 16);
            Bs = j.B2 + (size_t)kk * H;
        }
        float4 bv = *(const float4*)&Bs[bk * H + bn];
        __syncthreads();
        sA[ak + 0][am] = av.x; sA[ak + 1][am] = av.y;
        sA[ak + 2][am] = av.z; sA[ak + 3][am] = av.w;
        *(float4*)&sB[bk][bn] = bv;
        __syncthreads();
#pragma unroll
        for (int k = 0; k < BK; k++) {
            float a[8], bb[8];
            *(float4*)&a[0] = *(const float4*)&sA[k][ty * 8];
            *(float4*)&a[4] = *(const float4*)&sA[k][ty * 8 + 4];
            *(float4*)&bb[0] = *(const float4*)&sB[k][tx * 4];
            *(float4*)&bb[4] = *(const float4*)&sB[k][64 + tx * 4];
#pragma unroll
            for (int i = 0; i < 8; i++)
#pragma unroll
                for (int jj = 0; jj < 8; jj++)
                    acc[i][jj] += a[i] * bb[jj];
        }
    }
    float bcol[8];
    *(float4*)&bcol[0] = *(const float4*)&j.bias[tx * 4];
    *(float4*)&bcol[4] = *(const float4*)&j.bias[64 + tx * 4];
#pragma unroll
    for (int i = 0; i < 8; i++) {
        int gr = bm + ty * 8 + i;
        if (gr < j.M) {
            float4 o1, o2;
            o1.x = acc[i][0] + bcol[0]; o1.y = acc[i][1] + bcol[1];
            o1.z = acc[i][2] + bcol[2]; o1.w = acc[i][3] + bcol[3];
            o2.x = acc[i][4] + bcol[4]; o2.y = acc[i][5] + bcol[5];
            o2.z = acc[i][6] + bcol[6]; o2.w = acc[i][7] + bcol[7];
            if (j.relu) {
                o1.x = fmaxf(o1.x, 0.f); o1.y = fmaxf(o1.y, 0.f);
                o1.z = fmaxf(o1.z, 0.f); o1.w = fmaxf(o1.w, 0.f);
                o2.x = fmaxf(o2.x, 0.f); o2.y = fmaxf(o2.y, 0.f);
                o2.z = fmaxf(o2.z, 0.f); o2.w = fmaxf(o2.w, 0.f);
            }
            *(float4*)&j.C[(size_t)gr * H + tx * 4] = o1;
            *(float4*)&j.C[(size_t)gr * H + 64 + tx * 4] = o2;
            if (j.Cbf) {
                ushort4 u1, u2;
                u1.x = f2bf(o1.x); u1.y = f2bf(o1.y); u1.z = f2bf(o1.z); u1.w = f2bf(o1.w);
                u2.x = f2bf(o2.x); u2.y = f2bf(o2.y); u2.z = f2bf(o2.z); u2.w = f2bf(o2.w);
                *(ushort4*)&j.Cbf[(size_t)gr * H + tx * 4] = u1;
                *(ushort4*)&j.Cbf[(size_t)gr * H + 64 + tx * 4] = u2;
            }
        }
    }
}

// ============ launch ============

extern "C" void kernel_launch(void* const* d_in, const int* in_sizes, int n_in,
                              void* d_out, int out_size, void* d_ws, size_t ws_size,
                              hipStream_t stream) {
    const float* x_patient = (const float*)d_in[0];
    const float* x_concept = (const float*)d_in[1];
    const float* W_p       = (const float*)d_in[2];
    const float* b_p       = (const float*)d_in[3];
    const float* W_c       = (const float*)d_in[4];
    const float* b_c       = (const float*)d_in[5];
    const float* W_root    = (const float*)d_in[6];
    const float* b_root    = (const float*)d_in[7];
    const float* W_rel     = (const float*)d_in[8];
    const int*   src_pc    = (const int*)d_in[9];
    const int*   dst_pc    = (const int*)d_in[10];
    const int*   src_cp    = (const int*)d_in[11];
    const int*   dst_cp    = (const int*)d_in[12];
    float* out = (float*)d_out;

    char* w = (char*)d_ws;
    float* x0            = (float*)w;          w += (size_t)NN * H * 4;       // 35.8 MB
    unsigned short* xbf  = (unsigned short*)w; w += (size_t)NN * H * 2;       // 17.9 MB
    unsigned short* aggn = (unsigned short*)w; w += (size_t)SEGN * H * 2;     // 17.9 MB
    int* deg   = (int*)w;      w += (size_t)SEGN_PAD * 4;                     // 280 KB
    int* boff  = (int*)w;      w += (size_t)(NBUCK + 1) * 4;
    int* bcur  = (int*)w;      w += (size_t)NBUCK * 4;
    unsigned* pairs = (unsigned*)w; w += (size_t)2 * EE * 4;                  // 6.4 MB

    const int EB2 = (2 * EE + 255) / 256;

    // ---- bucket-grouped edge lists
    hipMemsetAsync(deg, 0, (size_t)SEGN_PAD * 4, stream);
    hist_kernel<<<EB2, 256, 0, stream>>>(dst_pc, dst_cp, deg);
    bucket_scan_kernel<<<1, 1024, 0, stream>>>(deg, boff, bcur);
    binpack_kernel<<<EB2, 256, 0, stream>>>(dst_pc, src_pc, dst_cp, src_cp, bcur, pairs);

    const int PB = (NPAT + BM - 1) / BM;  // 391
    const int CB = (NCON + BM - 1) / BM;  // 157

    // ---- projections -> x0 (fp32) + xbf (bf16)
    {
        GemmJob jp = { x_patient, nullptr, W_p, nullptr, b_p, x0, xbf,
                       64, 64, 0, NPAT, 0 };
        GemmJob jc = { x_concept, nullptr, W_c, nullptr, b_c,
                       x0 + (size_t)NPAT * H, xbf + (size_t)NPAT * H,
                       128, 128, 0, NCON, 0 };
        gemm_dual_kernel<<<PB + CB, 256, 0, stream>>>(jp, jc, PB);
    }

    // ---- layers: L0 x0->d_out, L1 d_out->x0, copy back
    const float* xin = x0;
    float* xout = out;
    for (int l = 0; l < 2; l++) {
        aggregate_kernel<<<NBUCK, 256, 0, stream>>>(xbf, pairs, boff, deg, aggn);
        const float* Wroot_l = W_root + (size_t)l * H * H;
        const float* Wrel_l0 = W_rel + (size_t)(l * 2 + 0) * H * H;
        const float* Wrel_l1 = W_rel + (size_t)(l * 2 + 1) * H * H;
        const float* br = b_root + (size_t)l * H;
        unsigned short* cbf_p = (l == 0) ? xbf : nullptr;
        unsigned short* cbf_c = (l == 0) ? xbf + (size_t)NPAT * H : nullptr;
        GemmJob jp = { xin, aggn + (size_t)NCON_AL * H, Wroot_l, Wrel_l1, br,
                       xout, cbf_p, H, H, H, NPAT, 1 };
        GemmJob jc = { xin + (size_t)NPAT * H, aggn, Wroot_l, Wrel_l0, br,
                       xout + (size_t)NPAT * H, cbf_c, H, H, H, NCON, 1 };
        gemm_dual_kernel<<<PB + CB, 256, 0, stream>>>(jp, jc, PB);
        xin = xout;
        xout = x0;
    }
    hipMemcpyAsync(out, x0, (size_t)NN * H * 4, hipMemcpyDeviceToDevice, stream);
}

// Round 4
// 876.276 us; speedup vs baseline: 3.6511x; 3.6511x over previous
//
#include <hip/hip_runtime.h>
#include <hip/hip_bf16.h>

#define NPAT 50000
#define NCON 20000
#define NN   70000
#define EE   800000
#define H    128

#define NCON_AL  20032                 // concepts padded to 64-alignment
#define SEGN     (NCON_AL + NPAT)      // 70032 segment ids
#define NBUCK    1095                  // ceil(SEGN/64)
#define SEGN_PAD (NBUCK * 64)          // 70080
#define RELSPLIT_B 313                 // buckets [0,313) = concept dsts (rel0)
#define CAP 8192                       // max edges per bucket (measured max ~2800)

typedef __attribute__((ext_vector_type(8))) short bf16x8;
typedef __attribute__((ext_vector_type(4))) float f32x4;

__device__ inline unsigned short f2bf(float f) {
    unsigned u = __float_as_uint(f);
    unsigned r = (u + 0x7FFFu + ((u >> 16) & 1u)) >> 16;
    return (unsigned short)r;
}
__device__ inline float bf2f_lo(unsigned v) { return __uint_as_float(v << 16); }
__device__ inline float bf2f_hi(unsigned v) { return __uint_as_float(v & 0xFFFF0000u); }

// ============ seg histogram ============
__global__ void hist_kernel(const int* __restrict__ dst_pc, const int* __restrict__ dst_cp,
                            int* __restrict__ deg) {
    int i = blockIdx.x * blockDim.x + threadIdx.x;
    if (i < EE) atomicAdd(&deg[dst_pc[i]], 1);
    else if (i < 2 * EE) atomicAdd(&deg[NCON_AL + dst_cp[i - EE]], 1);
}

// ============ bucket offsets: one block ============
__global__ __launch_bounds__(1024) void bucket_scan_kernel(const int* __restrict__ deg,
                                                           int* __restrict__ boff,
                                                           int* __restrict__ bcur) {
    int t = threadIdx.x;
    int s0 = 0, s1 = 0;
    if (2 * t < NBUCK) {
        const int4* p = (const int4*)&deg[2 * t * 64];
#pragma unroll
        for (int j = 0; j < 16; j++) { int4 v = p[j]; s0 += v.x + v.y + v.z + v.w; }
    }
    if (2 * t + 1 < NBUCK) {
        const int4* p = (const int4*)&deg[(2 * t + 1) * 64];
#pragma unroll
        for (int j = 0; j < 16; j++) { int4 v = p[j]; s1 += v.x + v.y + v.z + v.w; }
    }
    int s = s0 + s1;
    __shared__ int sm[1024];
    sm[t] = s;
    __syncthreads();
    for (int o = 1; o < 1024; o <<= 1) {
        int v = (t >= o) ? sm[t - o] : 0;
        __syncthreads();
        sm[t] += v;
        __syncthreads();
    }
    int pref = sm[t] - s;  // exclusive
    if (2 * t < NBUCK)     { boff[2 * t] = pref;          bcur[2 * t] = pref; }
    if (2 * t + 1 < NBUCK) { boff[2 * t + 1] = pref + s0; bcur[2 * t + 1] = pref + s0; }
    if (t == 1023) boff[NBUCK] = sm[1023];
}

// ============ binning: append packed (src | dl<<16) per 64-seg bucket ============
__global__ void binpack_kernel(const int* __restrict__ dst_pc, const int* __restrict__ src_pc,
                               const int* __restrict__ dst_cp, const int* __restrict__ src_cp,
                               int* __restrict__ bcur, unsigned* __restrict__ pairs) {
    int i = blockIdx.x * blockDim.x + threadIdx.x;
    int seg, src;
    if (i < EE)           { seg = dst_pc[i];                src = src_pc[i]; }
    else if (i < 2 * EE)  { seg = NCON_AL + dst_cp[i - EE]; src = src_cp[i - EE]; }
    else return;
    int b = seg >> 6;
    int pos = atomicAdd(&bcur[b], 1);
    pairs[pos] = (unsigned)src | ((unsigned)(seg & 63) << 16);
}

// ============ mean aggregation v2: block per bucket ============
// counting-sort pairs into per-dst-contiguous LDS list (1 LDS atomic/edge), then
// wave-per-dst gather-reduce in VGPRs (4-edge ILP), bf16 rows (256B/edge).
__global__ __launch_bounds__(256) void aggregate_kernel(
        const unsigned short* __restrict__ xbf, const unsigned* __restrict__ pairs,
        const int* __restrict__ boff, const int* __restrict__ deg,
        unsigned short* __restrict__ aggn) {
    __shared__ int soff[65];
    __shared__ int scur[64];
    __shared__ unsigned short ssrc[CAP];
    int tid = threadIdx.x;
    int b = blockIdx.x;
    int ebeg = boff[b], eend = boff[b + 1];
    if (tid < 64) {  // wave 0: exclusive scan of the 64 per-seg degrees
        int v = deg[b * 64 + tid];
        int s = v;
#pragma unroll
        for (int o = 1; o < 64; o <<= 1) {
            int u = __shfl_up(s, o);
            if (tid >= o) s += u;
        }
        soff[tid + 1] = s;
        if (tid == 0) soff[0] = 0;
        scur[tid] = s - v;
    }
    __syncthreads();
    for (int i = ebeg + tid; i < eend; i += 256) {
        unsigned p = pairs[i];
        int dl = p >> 16;
        int pos = atomicAdd(&scur[dl], 1);
        if (pos < CAP) ssrc[pos] = (unsigned short)(p & 0xFFFF);
    }
    __syncthreads();
    int wv = tid >> 6, lane = tid & 63;
    int rowbase = (b < RELSPLIT_B) ? 0 : NPAT;
    int seglim  = (b < RELSPLIT_B) ? NCON : SEGN;
    const unsigned* xw = (const unsigned*)xbf;   // 64 uints per row; lane covers cols 2l,2l+1
    for (int i = 0; i < 16; i++) {
        int d = wv * 16 + i;
        int seg = b * 64 + d;
        if (seg >= seglim) continue;
        int beg = soff[d], end = soff[d + 1];
        float2 A0 = {0.f, 0.f}, A1 = {0.f, 0.f}, A2 = {0.f, 0.f}, A3 = {0.f, 0.f};
        int jj = beg;
        for (; (jj & 3) && jj < end; jj++) {
            unsigned v = xw[(size_t)(rowbase + ssrc[jj]) * 64 + lane];
            A0.x += bf2f_lo(v); A0.y += bf2f_hi(v);
        }
        for (; jj + 3 < end; jj += 4) {
            ushort4 s4 = *(const ushort4*)&ssrc[jj];
            unsigned v0 = xw[(size_t)(rowbase + s4.x) * 64 + lane];
            unsigned v1 = xw[(size_t)(rowbase + s4.y) * 64 + lane];
            unsigned v2 = xw[(size_t)(rowbase + s4.z) * 64 + lane];
            unsigned v3 = xw[(size_t)(rowbase + s4.w) * 64 + lane];
            A0.x += bf2f_lo(v0); A0.y += bf2f_hi(v0);
            A1.x += bf2f_lo(v1); A1.y += bf2f_hi(v1);
            A2.x += bf2f_lo(v2); A2.y += bf2f_hi(v2);
            A3.x += bf2f_lo(v3); A3.y += bf2f_hi(v3);
        }
        for (; jj < end; jj++) {
            unsigned v = xw[(size_t)(rowbase + ssrc[jj]) * 64 + lane];
            A0.x += bf2f_lo(v); A0.y += bf2f_hi(v);
        }
        float inv = 1.0f / (float)max(end - beg, 1);
        ushort2 o;
        o.x = f2bf((A0.x + A1.x + A2.x + A3.x) * inv);
        o.y = f2bf((A0.y + A1.y + A2.y + A3.y) * inv);
        *(ushort2*)&aggn[(size_t)seg * H + 2 * lane] = o;  // zero-deg segs write 0 (required)
    }
}

// ============ proj GEMM (fp32 VALU): C/Cbf = A1 @ B1 + bias ============
#define BM 128
#define BK 8

struct GemmJob {
    const float* A1; const unsigned short* A2bf;
    const float* B1; const float* B2;
    const float* bias; float* C; unsigned short* Cbf;
    int lda1, K1, K2, M, relu;
};

__global__ void gemm_dual_kernel(GemmJob j0, GemmJob j1, int nb0) {
    __shared__ float sA[BK][BM];
    __shared__ float sB[BK][H];
    bool first = (int)blockIdx.x < nb0;
    GemmJob j = first ? j0 : j1;
    int bm = (first ? blockIdx.x : blockIdx.x - nb0) * BM;
    int tid = threadIdx.x;
    int am = tid >> 1;
    int ak = (tid & 1) * 4;
    int bk = tid >> 5;
    int bn = (tid & 31) * 4;
    int ty = tid >> 4;
    int tx = tid & 15;
    float acc[8][8] = {};
    int Ktot = j.K1 + j.K2;
    for (int k0 = 0; k0 < Ktot; k0 += BK) {
        int gm = bm + am; if (gm >= j.M) gm = j.M - 1;
        float4 av;
        const float* Bs;
        if (k0 < j.K1) {
            av = *(const float4*)&j.A1[(size_t)gm * j.lda1 + k0 + ak];
            Bs = j.B1 + (size_t)k0 * H;
        } else {
            int kk = k0 - j.K1;
            ushort4 uv = *(const ushort4*)&j.A2bf[(size_t)gm * H + kk + ak];
            av.x = __uint_as_float((unsigned)uv.x << 16);
            av.y = __uint_as_float((unsigned)uv.y << 16);
            av.z = __uint_as_float((unsigned)uv.z << 16);
            av.w = __uint_as_float((unsigned)uv.w << 16);
            Bs = j.B2 + (size_t)kk * H;
        }
        float4 bv = *(const float4*)&Bs[bk * H + bn];
        __syncthreads();
        sA[ak + 0][am] = av.x; sA[ak + 1][am] = av.y;
        sA[ak + 2][am] = av.z; sA[ak + 3][am] = av.w;
        *(float4*)&sB[bk][bn] = bv;
        __syncthreads();
#pragma unroll
        for (int k = 0; k < BK; k++) {
            float a[8], bb[8];
            *(float4*)&a[0] = *(const float4*)&sA[k][ty * 8];
            *(float4*)&a[4] = *(const float4*)&sA[k][ty * 8 + 4];
            *(float4*)&bb[0] = *(const float4*)&sB[k][tx * 4];
            *(float4*)&bb[4] = *(const float4*)&sB[k][64 + tx * 4];
#pragma unroll
            for (int i = 0; i < 8; i++)
#pragma unroll
                for (int jj = 0; jj < 8; jj++)
                    acc[i][jj] += a[i] * bb[jj];
        }
    }
    float bcol[8];
    *(float4*)&bcol[0] = *(const float4*)&j.bias[tx * 4];
    *(float4*)&bcol[4] = *(const float4*)&j.bias[64 + tx * 4];
#pragma unroll
    for (int i = 0; i < 8; i++) {
        int gr = bm + ty * 8 + i;
        if (gr < j.M) {
#pragma unroll
            for (int q = 0; q < 8; q++) {
                float v = acc[i][q] + bcol[q];
                if (j.relu) v = fmaxf(v, 0.f);
                int gc = (q < 4) ? (tx * 4 + q) : (64 + tx * 4 + q - 4);
                if (j.C)   j.C[(size_t)gr * H + gc] = v;
                if (j.Cbf) j.Cbf[(size_t)gr * H + gc] = f2bf(v);
            }
        }
    }
}

// ============ layer GEMM (bf16 MFMA): C = [A1|A2] @ bf16([B1;B2]) + bias, relu ======
// 128x128 tile, 4 waves in 2x2, each wave 4x4 16x16x32 MFMA tiles, K=256 in 8 steps.
struct MJob {
    const unsigned short* A1;  // [M][H] bf16
    const unsigned short* A2;  // [M][H] bf16
    const float* B1;           // [H][H] fp32 k-major
    const float* B2;
    const float* bias;
    float* C;                  // fp32 or null
    unsigned short* Cbf;       // bf16 or null
    int M;
};

__global__ __launch_bounds__(256) void gemm_mfma_kernel(MJob j0, MJob j1, int nb0) {
    __shared__ unsigned short sA[128][40];   // [row][k] pad 32->40 (2-way banks)
    __shared__ unsigned short sBT[128][40];  // [col][k]
    bool first = (int)blockIdx.x < nb0;
    MJob J = first ? j0 : j1;
    int bm = (first ? (int)blockIdx.x : (int)blockIdx.x - nb0) * 128;
    int tid = threadIdx.x;
    int wv = tid >> 6, lane = tid & 63;
    int wr = wv >> 1, wc = wv & 1;
    int m16 = lane & 15, kg = lane >> 4;

    f32x4 acc[4][4];
#pragma unroll
    for (int a = 0; a < 4; a++)
#pragma unroll
        for (int c = 0; c < 4; c++) acc[a][c] = (f32x4){0.f, 0.f, 0.f, 0.f};

    int ar = tid >> 1, ah = tid & 1;         // A staging: row, 16-elem half
    int gmA = bm + ar; if (gmA >= J.M) gmA = J.M - 1;
    int bn = tid & 127, bk0 = tid >> 7;      // B staging: col, k parity

#pragma unroll
    for (int kt = 0; kt < 8; kt++) {
        int k0 = kt * 32;
        const unsigned short* asrc = (k0 < 128)
            ? (J.A1 + (size_t)gmA * H + k0)
            : (J.A2 + (size_t)gmA * H + (k0 - 128));
        const uint4* a4 = (const uint4*)(asrc + ah * 16);
        uint4 av0 = a4[0], av1 = a4[1];
        const float* bsrc = (k0 < 128) ? (J.B1 + (size_t)k0 * H)
                                       : (J.B2 + (size_t)(k0 - 128) * H);
        float bvals[16];
#pragma unroll
        for (int kk = 0; kk < 16; kk++) bvals[kk] = bsrc[(size_t)(2 * kk + bk0) * H + bn];
        __syncthreads();
        { uint4* d4 = (uint4*)&sA[ar][ah * 16]; d4[0] = av0; d4[1] = av1; }
#pragma unroll
        for (int kk = 0; kk < 16; kk++) sBT[bn][2 * kk + bk0] = f2bf(bvals[kk]);
        __syncthreads();
        bf16x8 af[4], bfg[4];
#pragma unroll
        for (int mt = 0; mt < 4; mt++)
            af[mt] = *(bf16x8*)&sA[wr * 64 + mt * 16 + m16][kg * 8];
#pragma unroll
        for (int nt = 0; nt < 4; nt++)
            bfg[nt] = *(bf16x8*)&sBT[wc * 64 + nt * 16 + m16][kg * 8];
#pragma unroll
        for (int mt = 0; mt < 4; mt++)
#pragma unroll
            for (int nt = 0; nt < 4; nt++)
                acc[mt][nt] = __builtin_amdgcn_mfma_f32_16x16x32_bf16(
                    af[mt], bfg[nt], acc[mt][nt], 0, 0, 0);
    }
    float bv[4];
#pragma unroll
    for (int nt = 0; nt < 4; nt++) bv[nt] = J.bias[wc * 64 + nt * 16 + m16];
#pragma unroll
    for (int mt = 0; mt < 4; mt++) {
        int gr0 = bm + wr * 64 + mt * 16 + kg * 4;
#pragma unroll
        for (int r = 0; r < 4; r++) {
            int gr = gr0 + r;
            if (gr < J.M) {
#pragma unroll
                for (int nt = 0; nt < 4; nt++) {
                    int gc = wc * 64 + nt * 16 + m16;
                    float v = fmaxf(acc[mt][nt][r] + bv[nt], 0.f);
                    if (J.C)   J.C[(size_t)gr * H + gc] = v;
                    if (J.Cbf) J.Cbf[(size_t)gr * H + gc] = f2bf(v);
                }
            }
        }
    }
}

// ============ launch ============

extern "C" void kernel_launch(void* const* d_in, const int* in_sizes, int n_in,
                              void* d_out, int out_size, void* d_ws, size_t ws_size,
                              hipStream_t stream) {
    const float* x_patient = (const float*)d_in[0];
    const float* x_concept = (const float*)d_in[1];
    const float* W_p       = (const float*)d_in[2];
    const float* b_p       = (const float*)d_in[3];
    const float* W_c       = (const float*)d_in[4];
    const float* b_c       = (const float*)d_in[5];
    const float* W_root    = (const float*)d_in[6];
    const float* b_root    = (const float*)d_in[7];
    const float* W_rel     = (const float*)d_in[8];
    const int*   src_pc    = (const int*)d_in[9];
    const int*   dst_pc    = (const int*)d_in[10];
    const int*   src_cp    = (const int*)d_in[11];
    const int*   dst_cp    = (const int*)d_in[12];
    float* out = (float*)d_out;

    char* w = (char*)d_ws;
    unsigned short* xbf  = (unsigned short*)w; w += (size_t)NN * H * 2;     // 17.9 MB
    unsigned short* aggn = (unsigned short*)w; w += (size_t)SEGN * H * 2;   // 17.9 MB
    int* deg   = (int*)w;      w += (size_t)SEGN_PAD * 4;
    int* boff  = (int*)w;      w += (size_t)(NBUCK + 1) * 4;
    int* bcur  = (int*)w;      w += (size_t)NBUCK * 4;
    unsigned* pairs = (unsigned*)w; w += (size_t)2 * EE * 4;                // 6.4 MB

    const int EB2 = (2 * EE + 255) / 256;

    hipMemsetAsync(deg, 0, (size_t)SEGN_PAD * 4, stream);
    hist_kernel<<<EB2, 256, 0, stream>>>(dst_pc, dst_cp, deg);
    bucket_scan_kernel<<<1, 1024, 0, stream>>>(deg, boff, bcur);
    binpack_kernel<<<EB2, 256, 0, stream>>>(dst_pc, src_pc, dst_cp, src_cp, bcur, pairs);

    const int PB = (NPAT + BM - 1) / BM;  // 391
    const int CB = (NCON + BM - 1) / BM;  // 157

    // projections -> xbf only (bf16 chain; fp32 x never needed again)
    {
        GemmJob jp = { x_patient, nullptr, W_p, nullptr, b_p, nullptr, xbf,
                       64, 64, 0, NPAT, 0 };
        GemmJob jc = { x_concept, nullptr, W_c, nullptr, b_c, nullptr,
                       xbf + (size_t)NPAT * H, 128, 128, 0, NCON, 0 };
        gemm_dual_kernel<<<PB + CB, 256, 0, stream>>>(jp, jc, PB);
    }

    for (int l = 0; l < 2; l++) {
        aggregate_kernel<<<NBUCK, 256, 0, stream>>>(xbf, pairs, boff, deg, aggn);
        const float* Wroot_l = W_root + (size_t)l * H * H;
        const float* Wrel_l0 = W_rel + (size_t)(l * 2 + 0) * H * H;
        const float* Wrel_l1 = W_rel + (size_t)(l * 2 + 1) * H * H;
        const float* br = b_root + (size_t)l * H;
        float* cp = (l == 1) ? out : nullptr;
        float* cc = (l == 1) ? out + (size_t)NPAT * H : nullptr;
        unsigned short* bp = (l == 0) ? xbf : nullptr;                       // in-place ok
        unsigned short* bc = (l == 0) ? xbf + (size_t)NPAT * H : nullptr;
        MJob jp = { xbf, aggn + (size_t)NCON_AL * H, Wroot_l, Wrel_l1, br,
                    cp, bp, NPAT };
        MJob jc = { xbf + (size_t)NPAT * H, aggn, Wroot_l, Wrel_l0, br,
                    cc, bc, NCON };
        gemm_mfma_kernel<<<PB + CB, 256, 0, stream>>>(jp, jc, PB);
    }
}

// Round 5
// 619.910 us; speedup vs baseline: 5.1611x; 1.4136x over previous
//
#include <hip/hip_runtime.h>
#include <hip/hip_bf16.h>

#define NPAT 50000
#define NCON 20000
#define NN   70000
#define EE   800000
#define H    128

#define NCON_AL  20032                 // concepts padded to 64-alignment
#define SEGN     (NCON_AL + NPAT)      // 70032 segment ids
#define NBUCK    1095                  // ceil(SEGN/64)
#define SEGN_PAD (NBUCK * 64)          // 70080
#define RELSPLIT_B 313                 // buckets [0,313) = concept dsts (rel0)
#define CAP 8192                       // max edges per bucket (measured max ~2800)
#define SUBS 16                        // sub-cursors per bucket (contention /16)
#define NSUB (NBUCK * SUBS)            // 17520

typedef __attribute__((ext_vector_type(8))) short bf16x8;
typedef __attribute__((ext_vector_type(4))) float f32x4;

__device__ inline unsigned short f2bf(float f) {
    unsigned u = __float_as_uint(f);
    unsigned r = (u + 0x7FFFu + ((u >> 16) & 1u)) >> 16;
    return (unsigned short)r;
}
__device__ inline float bf2f_lo(unsigned v) { return __uint_as_float(v << 16); }
__device__ inline float bf2f_hi(unsigned v) { return __uint_as_float(v & 0xFFFF0000u); }

// ============ histogram: per-seg degree + per-(bucket,sub) counts ============
__global__ void hist_kernel(const int* __restrict__ dst_pc, const int* __restrict__ dst_cp,
                            int* __restrict__ deg, int* __restrict__ subcnt) {
    int i = blockIdx.x * blockDim.x + threadIdx.x;
    int seg;
    if (i < EE)          seg = dst_pc[i];
    else if (i < 2 * EE) seg = NCON_AL + dst_cp[i - EE];
    else return;
    atomicAdd(&deg[seg], 1);
    int sub = (i >> 8) & (SUBS - 1);   // block-uniform hash; MUST match binpack
    atomicAdd(&subcnt[(seg >> 6) * SUBS + sub], 1);
}

// ============ scan over (bucket,sub) counts -> subcur bases + bucket offsets ======
__global__ __launch_bounds__(1024) void scan_sub_kernel(const int* __restrict__ subcnt,
                                                        int* __restrict__ subcur,
                                                        int* __restrict__ boff) {
    int t = threadIdx.x;
    const int PER = (NSUB + 1023) / 1024;   // 18
    int beg = t * PER, end = min(beg + PER, NSUB);
    int s = 0;
    for (int i = beg; i < end; i++) s += subcnt[i];
    __shared__ int sm[1024];
    sm[t] = s;
    __syncthreads();
    for (int o = 1; o < 1024; o <<= 1) {
        int v = (t >= o) ? sm[t - o] : 0;
        __syncthreads();
        sm[t] += v;
        __syncthreads();
    }
    int run = sm[t] - s;  // exclusive prefix
    for (int i = beg; i < end; i++) {
        subcur[i] = run;
        if ((i & (SUBS - 1)) == 0) boff[i / SUBS] = run;
        run += subcnt[i];
    }
    if (t == 1023) boff[NBUCK] = sm[1023];
}

// ============ binning: append packed (src | dl<<16) per (bucket,sub) region ======
__global__ void binpack_kernel(const int* __restrict__ dst_pc, const int* __restrict__ src_pc,
                               const int* __restrict__ dst_cp, const int* __restrict__ src_cp,
                               int* __restrict__ subcur, unsigned* __restrict__ pairs) {
    int i = blockIdx.x * blockDim.x + threadIdx.x;
    int seg, src;
    if (i < EE)           { seg = dst_pc[i];                src = src_pc[i]; }
    else if (i < 2 * EE)  { seg = NCON_AL + dst_cp[i - EE]; src = src_cp[i - EE]; }
    else return;
    int sub = (i >> 8) & (SUBS - 1);
    int pos = atomicAdd(&subcur[(seg >> 6) * SUBS + sub], 1);
    pairs[pos] = (unsigned)src | ((unsigned)(seg & 63) << 16);
}

// ============ mean aggregation: block per bucket ============
// counting-sort pairs into per-dst-contiguous LDS list (1 LDS atomic/edge), then
// wave-per-dst gather-reduce in VGPRs (4-edge ILP), bf16 rows (256B/edge).
__global__ __launch_bounds__(256) void aggregate_kernel(
        const unsigned short* __restrict__ xbf, const unsigned* __restrict__ pairs,
        const int* __restrict__ boff, const int* __restrict__ deg,
        unsigned short* __restrict__ aggn) {
    __shared__ int soff[65];
    __shared__ int scur[64];
    __shared__ unsigned short ssrc[CAP];
    int tid = threadIdx.x;
    int b = blockIdx.x;
    int ebeg = boff[b], eend = boff[b + 1];
    if (tid < 64) {  // wave 0: exclusive scan of the 64 per-seg degrees
        int v = deg[b * 64 + tid];
        int s = v;
#pragma unroll
        for (int o = 1; o < 64; o <<= 1) {
            int u = __shfl_up(s, o);
            if (tid >= o) s += u;
        }
        soff[tid + 1] = s;
        if (tid == 0) soff[0] = 0;
        scur[tid] = s - v;
    }
    __syncthreads();
    for (int i = ebeg + tid; i < eend; i += 256) {
        unsigned p = pairs[i];
        int dl = p >> 16;
        int pos = atomicAdd(&scur[dl], 1);
        if (pos < CAP) ssrc[pos] = (unsigned short)(p & 0xFFFF);
    }
    __syncthreads();
    int wv = tid >> 6, lane = tid & 63;
    int rowbase = (b < RELSPLIT_B) ? 0 : NPAT;
    int seglim  = (b < RELSPLIT_B) ? NCON : SEGN;
    const unsigned* xw = (const unsigned*)xbf;   // 64 uints per row; lane covers cols 2l,2l+1
    for (int i = 0; i < 16; i++) {
        int d = wv * 16 + i;
        int seg = b * 64 + d;
        if (seg >= seglim) continue;
        int beg = soff[d], end = soff[d + 1];
        float2 A0 = {0.f, 0.f}, A1 = {0.f, 0.f}, A2 = {0.f, 0.f}, A3 = {0.f, 0.f};
        int jj = beg;
        for (; (jj & 3) && jj < end; jj++) {
            unsigned v = xw[(size_t)(rowbase + ssrc[jj]) * 64 + lane];
            A0.x += bf2f_lo(v); A0.y += bf2f_hi(v);
        }
        for (; jj + 3 < end; jj += 4) {
            ushort4 s4 = *(const ushort4*)&ssrc[jj];
            unsigned v0 = xw[(size_t)(rowbase + s4.x) * 64 + lane];
            unsigned v1 = xw[(size_t)(rowbase + s4.y) * 64 + lane];
            unsigned v2 = xw[(size_t)(rowbase + s4.z) * 64 + lane];
            unsigned v3 = xw[(size_t)(rowbase + s4.w) * 64 + lane];
            A0.x += bf2f_lo(v0); A0.y += bf2f_hi(v0);
            A1.x += bf2f_lo(v1); A1.y += bf2f_hi(v1);
            A2.x += bf2f_lo(v2); A2.y += bf2f_hi(v2);
            A3.x += bf2f_lo(v3); A3.y += bf2f_hi(v3);
        }
        for (; jj < end; jj++) {
            unsigned v = xw[(size_t)(rowbase + ssrc[jj]) * 64 + lane];
            A0.x += bf2f_lo(v); A0.y += bf2f_hi(v);
        }
        float inv = 1.0f / (float)max(end - beg, 1);
        ushort2 o;
        o.x = f2bf((A0.x + A1.x + A2.x + A3.x) * inv);
        o.y = f2bf((A0.y + A1.y + A2.y + A3.y) * inv);
        *(ushort2*)&aggn[(size_t)seg * H + 2 * lane] = o;  // zero-deg segs write 0 (required)
    }
}

// ============ proj GEMM (fp32 VALU): Cbf = A1 @ B1 + bias ============
#define BM 128
#define BK 8

struct GemmJob {
    const float* A1; const unsigned short* A2bf;
    const float* B1; const float* B2;
    const float* bias; float* C; unsigned short* Cbf;
    int lda1, K1, K2, M, relu;
};

__global__ void gemm_dual_kernel(GemmJob j0, GemmJob j1, int nb0) {
    __shared__ float sA[BK][BM];
    __shared__ float sB[BK][H];
    bool first = (int)blockIdx.x < nb0;
    GemmJob j = first ? j0 : j1;
    int bm = (first ? blockIdx.x : blockIdx.x - nb0) * BM;
    int tid = threadIdx.x;
    int am = tid >> 1;
    int ak = (tid & 1) * 4;
    int bk = tid >> 5;
    int bn = (tid & 31) * 4;
    int ty = tid >> 4;
    int tx = tid & 15;
    float acc[8][8] = {};
    int Ktot = j.K1 + j.K2;
    for (int k0 = 0; k0 < Ktot; k0 += BK) {
        int gm = bm + am; if (gm >= j.M) gm = j.M - 1;
        float4 av;
        const float* Bs;
        if (k0 < j.K1) {
            av = *(const float4*)&j.A1[(size_t)gm * j.lda1 + k0 + ak];
            Bs = j.B1 + (size_t)k0 * H;
        } else {
            int kk = k0 - j.K1;
            ushort4 uv = *(const ushort4*)&j.A2bf[(size_t)gm * H + kk + ak];
            av.x = __uint_as_float((unsigned)uv.x << 16);
            av.y = __uint_as_float((unsigned)uv.y << 16);
            av.z = __uint_as_float((unsigned)uv.z << 16);
            av.w = __uint_as_float((unsigned)uv.w << 16);
            Bs = j.B2 + (size_t)kk * H;
        }
        float4 bv = *(const float4*)&Bs[bk * H + bn];
        __syncthreads();
        sA[ak + 0][am] = av.x; sA[ak + 1][am] = av.y;
        sA[ak + 2][am] = av.z; sA[ak + 3][am] = av.w;
        *(float4*)&sB[bk][bn] = bv;
        __syncthreads();
#pragma unroll
        for (int k = 0; k < BK; k++) {
            float a[8], bb[8];
            *(float4*)&a[0] = *(const float4*)&sA[k][ty * 8];
            *(float4*)&a[4] = *(const float4*)&sA[k][ty * 8 + 4];
            *(float4*)&bb[0] = *(const float4*)&sB[k][tx * 4];
            *(float4*)&bb[4] = *(const float4*)&sB[k][64 + tx * 4];
#pragma unroll
            for (int i = 0; i < 8; i++)
#pragma unroll
                for (int jj = 0; jj < 8; jj++)
                    acc[i][jj] += a[i] * bb[jj];
        }
    }
    float bcol[8];
    *(float4*)&bcol[0] = *(const float4*)&j.bias[tx * 4];
    *(float4*)&bcol[4] = *(const float4*)&j.bias[64 + tx * 4];
#pragma unroll
    for (int i = 0; i < 8; i++) {
        int gr = bm + ty * 8 + i;
        if (gr < j.M) {
#pragma unroll
            for (int q = 0; q < 8; q++) {
                float v = acc[i][q] + bcol[q];
                if (j.relu) v = fmaxf(v, 0.f);
                int gc = (q < 4) ? (tx * 4 + q) : (64 + tx * 4 + q - 4);
                if (j.C)   j.C[(size_t)gr * H + gc] = v;
                if (j.Cbf) j.Cbf[(size_t)gr * H + gc] = f2bf(v);
            }
        }
    }
}

// ============ layer GEMM (bf16 MFMA): C = [A1|A2] @ bf16([B1;B2]) + bias, relu ======
struct MJob {
    const unsigned short* A1;  // [M][H] bf16
    const unsigned short* A2;  // [M][H] bf16
    const float* B1;           // [H][H] fp32 k-major
    const float* B2;
    const float* bias;
    float* C;                  // fp32 or null
    unsigned short* Cbf;       // bf16 or null
    int M;
};

__global__ __launch_bounds__(256) void gemm_mfma_kernel(MJob j0, MJob j1, int nb0) {
    __shared__ unsigned short sA[128][40];   // [row][k] pad 32->40
    __shared__ unsigned short sBT[128][40];  // [col][k]
    bool first = (int)blockIdx.x < nb0;
    MJob J = first ? j0 : j1;
    int bm = (first ? (int)blockIdx.x : (int)blockIdx.x - nb0) * 128;
    int tid = threadIdx.x;
    int wv = tid >> 6, lane = tid & 63;
    int wr = wv >> 1, wc = wv & 1;
    int m16 = lane & 15, kg = lane >> 4;

    f32x4 acc[4][4];
#pragma unroll
    for (int a = 0; a < 4; a++)
#pragma unroll
        for (int c = 0; c < 4; c++) acc[a][c] = (f32x4){0.f, 0.f, 0.f, 0.f};

    int ar = tid >> 1, ah = tid & 1;
    int gmA = bm + ar; if (gmA >= J.M) gmA = J.M - 1;
    int bn = tid & 127, bk0 = tid >> 7;

#pragma unroll
    for (int kt = 0; kt < 8; kt++) {
        int k0 = kt * 32;
        const unsigned short* asrc = (k0 < 128)
            ? (J.A1 + (size_t)gmA * H + k0)
            : (J.A2 + (size_t)gmA * H + (k0 - 128));
        const uint4* a4 = (const uint4*)(asrc + ah * 16);
        uint4 av0 = a4[0], av1 = a4[1];
        const float* bsrc = (k0 < 128) ? (J.B1 + (size_t)k0 * H)
                                       : (J.B2 + (size_t)(k0 - 128) * H);
        float bvals[16];
#pragma unroll
        for (int kk = 0; kk < 16; kk++) bvals[kk] = bsrc[(size_t)(2 * kk + bk0) * H + bn];
        __syncthreads();
        { uint4* d4 = (uint4*)&sA[ar][ah * 16]; d4[0] = av0; d4[1] = av1; }
#pragma unroll
        for (int kk = 0; kk < 16; kk++) sBT[bn][2 * kk + bk0] = f2bf(bvals[kk]);
        __syncthreads();
        bf16x8 af[4], bfg[4];
#pragma unroll
        for (int mt = 0; mt < 4; mt++)
            af[mt] = *(bf16x8*)&sA[wr * 64 + mt * 16 + m16][kg * 8];
#pragma unroll
        for (int nt = 0; nt < 4; nt++)
            bfg[nt] = *(bf16x8*)&sBT[wc * 64 + nt * 16 + m16][kg * 8];
#pragma unroll
        for (int mt = 0; mt < 4; mt++)
#pragma unroll
            for (int nt = 0; nt < 4; nt++)
                acc[mt][nt] = __builtin_amdgcn_mfma_f32_16x16x32_bf16(
                    af[mt], bfg[nt], acc[mt][nt], 0, 0, 0);
    }
    float bv[4];
#pragma unroll
    for (int nt = 0; nt < 4; nt++) bv[nt] = J.bias[wc * 64 + nt * 16 + m16];
#pragma unroll
    for (int mt = 0; mt < 4; mt++) {
        int gr0 = bm + wr * 64 + mt * 16 + kg * 4;
#pragma unroll
        for (int r = 0; r < 4; r++) {
            int gr = gr0 + r;
            if (gr < J.M) {
#pragma unroll
                for (int nt = 0; nt < 4; nt++) {
                    int gc = wc * 64 + nt * 16 + m16;
                    float v = fmaxf(acc[mt][nt][r] + bv[nt], 0.f);
                    if (J.C)   J.C[(size_t)gr * H + gc] = v;
                    if (J.Cbf) J.Cbf[(size_t)gr * H + gc] = f2bf(v);
                }
            }
        }
    }
}

// ============ launch ============

extern "C" void kernel_launch(void* const* d_in, const int* in_sizes, int n_in,
                              void* d_out, int out_size, void* d_ws, size_t ws_size,
                              hipStream_t stream) {
    const float* x_patient = (const float*)d_in[0];
    const float* x_concept = (const float*)d_in[1];
    const float* W_p       = (const float*)d_in[2];
    const float* b_p       = (const float*)d_in[3];
    const float* W_c       = (const float*)d_in[4];
    const float* b_c       = (const float*)d_in[5];
    const float* W_root    = (const float*)d_in[6];
    const float* b_root    = (const float*)d_in[7];
    const float* W_rel     = (const float*)d_in[8];
    const int*   src_pc    = (const int*)d_in[9];
    const int*   dst_pc    = (const int*)d_in[10];
    const int*   src_cp    = (const int*)d_in[11];
    const int*   dst_cp    = (const int*)d_in[12];
    float* out = (float*)d_out;

    char* w = (char*)d_ws;
    unsigned short* xbf  = (unsigned short*)w; w += (size_t)NN * H * 2;     // 17.9 MB
    unsigned short* aggn = (unsigned short*)w; w += (size_t)SEGN * H * 2;   // 17.9 MB
    int* deg    = (int*)w;     w += (size_t)SEGN_PAD * 4;                   // memset'd
    int* subcnt = (int*)w;     w += (size_t)NSUB * 4;                       // memset'd (contig w/ deg)
    int* subcur = (int*)w;     w += (size_t)NSUB * 4;
    int* boff   = (int*)w;     w += (size_t)(NBUCK + 1) * 4;
    unsigned* pairs = (unsigned*)w; w += (size_t)2 * EE * 4;                // 6.4 MB

    const int EB2 = (2 * EE + 255) / 256;

    hipMemsetAsync(deg, 0, (size_t)(SEGN_PAD + NSUB) * 4, stream);
    hist_kernel<<<EB2, 256, 0, stream>>>(dst_pc, dst_cp, deg, subcnt);
    scan_sub_kernel<<<1, 1024, 0, stream>>>(subcnt, subcur, boff);
    binpack_kernel<<<EB2, 256, 0, stream>>>(dst_pc, src_pc, dst_cp, src_cp, subcur, pairs);

    const int PB = (NPAT + BM - 1) / BM;  // 391
    const int CB = (NCON + BM - 1) / BM;  // 157

    // projections -> xbf only
    {
        GemmJob jp = { x_patient, nullptr, W_p, nullptr, b_p, nullptr, xbf,
                       64, 64, 0, NPAT, 0 };
        GemmJob jc = { x_concept, nullptr, W_c, nullptr, b_c, nullptr,
                       xbf + (size_t)NPAT * H, 128, 128, 0, NCON, 0 };
        gemm_dual_kernel<<<PB + CB, 256, 0, stream>>>(jp, jc, PB);
    }

    for (int l = 0; l < 2; l++) {
        aggregate_kernel<<<NBUCK, 256, 0, stream>>>(xbf, pairs, boff, deg, aggn);
        const float* Wroot_l = W_root + (size_t)l * H * H;
        const float* Wrel_l0 = W_rel + (size_t)(l * 2 + 0) * H * H;
        const float* Wrel_l1 = W_rel + (size_t)(l * 2 + 1) * H * H;
        const float* br = b_root + (size_t)l * H;
        float* cp = (l == 1) ? out : nullptr;
        float* cc = (l == 1) ? out + (size_t)NPAT * H : nullptr;
        unsigned short* bp = (l == 0) ? xbf : nullptr;                       // in-place ok
        unsigned short* bc = (l == 0) ? xbf + (size_t)NPAT * H : nullptr;
        MJob jp = { xbf, aggn + (size_t)NCON_AL * H, Wroot_l, Wrel_l1, br,
                    cp, bp, NPAT };
        MJob jc = { xbf + (size_t)NPAT * H, aggn, Wroot_l, Wrel_l0, br,
                    cc, bc, NCON };
        gemm_mfma_kernel<<<PB + CB, 256, 0, stream>>>(jp, jc, PB);
    }
}

// Round 6
// 382.093 us; speedup vs baseline: 8.3733x; 1.6224x over previous
//
#include <hip/hip_runtime.h>
#include <hip/hip_bf16.h>

#define NPAT 50000
#define NCON 20000
#define NN   70000
#define EE   800000
#define H    128

#define NCON_AL  20032                 // concepts padded to 64-alignment
#define SEGN     (NCON_AL + NPAT)      // 70032 segment ids
#define NBUCK    1095                  // ceil(SEGN/64)
#define RELSPLIT_B 313                 // buckets [0,313) = concept dsts (rel0)
#define BUCKCAP  5120                  // pairs capacity per bucket (max fill ~2900)
#define SUBS     16                    // sub-regions per bucket (reservation slots)
#define SUBCAP   (BUCKCAP / SUBS)      // 320 (max fill ~236)
#define BPE      4096                  // edges per binpack block
#define NBB      ((2 * EE + BPE - 1) / BPE)   // 391
#define CAP      4096                  // aggregate LDS edge capacity (max bucket ~2900)

typedef __attribute__((ext_vector_type(8))) short bf16x8;
typedef __attribute__((ext_vector_type(4))) float f32x4;

__device__ inline unsigned short f2bf(float f) {
    unsigned u = __float_as_uint(f);
    unsigned r = (u + 0x7FFFu + ((u >> 16) & 1u)) >> 16;
    return (unsigned short)r;
}
__device__ inline float bf2f_lo(unsigned v) { return __uint_as_float(v << 16); }
__device__ inline float bf2f_hi(unsigned v) { return __uint_as_float(v & 0xFFFF0000u); }

// ============ init: per-(bucket,sub) cursors at static bases ============
__global__ void init_gcur_kernel(int* __restrict__ gcur) {
    int j = blockIdx.x * 256 + threadIdx.x;
    if (j < NBUCK * SUBS) gcur[j] = (j >> 4) * BUCKCAP + (j & (SUBS - 1)) * SUBCAP;
}

// ============ binpack: block-local LDS counting sort by bucket, run-reserve, coalesced write ====
__global__ __launch_bounds__(256) void binpack_kernel(
        const int* __restrict__ dst_pc, const int* __restrict__ src_pc,
        const int* __restrict__ dst_cp, const int* __restrict__ src_cp,
        int* __restrict__ gcur, unsigned* __restrict__ pairs) {
    __shared__ unsigned sval[BPE];       // 16 KB
    __shared__ int saddr[BPE];           // 16 KB
    __shared__ int cnt[NBUCK];           // 4.4 KB (becomes local cursor in place phase)
    __shared__ int delta[NBUCK];         // 4.4 KB
    __shared__ int partial[256];
    int t = threadIdx.x, blk = blockIdx.x;
    int base = blk * BPE;
    int n = min(BPE, 2 * EE - base);

    for (int i = t; i < NBUCK; i += 256) cnt[i] = 0;
    __syncthreads();

    unsigned pay[16];
    int bkt[16];
#pragma unroll
    for (int q = 0; q < 16; q++) {
        int li = q * 256 + t;
        bkt[q] = -1;
        if (li < n) {
            int i = base + li;
            int seg, src;
            if (i < EE) { seg = dst_pc[i];                src = src_pc[i]; }
            else        { seg = NCON_AL + dst_cp[i - EE]; src = src_cp[i - EE]; }
            int b = seg >> 6;
            pay[q] = (unsigned)src | ((unsigned)(seg & 63) << 16);
            bkt[q] = b;
            atomicAdd(&cnt[b], 1);
        }
    }
    __syncthreads();

    // exclusive scan of cnt[0..NBUCK) -> pref (stored back into... need cnt kept for reserve;
    // compute pref per-thread chunk, keep in regs, write after reserve reads cnt)
    const int PER = (NBUCK + 255) / 256;   // 5
    int beg = t * PER;
    int s = 0;
#pragma unroll
    for (int k = 0; k < PER; k++) { int i = beg + k; if (i < NBUCK) s += cnt[i]; }
    partial[t] = s;
    __syncthreads();
    for (int o = 1; o < 256; o <<= 1) {
        int v = (t >= o) ? partial[t - o] : 0;
        __syncthreads();
        partial[t] += v;
        __syncthreads();
    }
    int run = partial[t] - s;
    int sub = blk & (SUBS - 1);
    int prefk[PER];
#pragma unroll
    for (int k = 0; k < PER; k++) {
        int i = beg + k;
        if (i < NBUCK) {
            prefk[k] = run;
            int c = cnt[i];
            if (c > 0) {
                int gb = atomicAdd(&gcur[i * SUBS + sub], c);
                delta[i] = gb - run;
            }
            run += c;
        }
    }
    __syncthreads();
    // turn cnt[] into local cursors = pref
#pragma unroll
    for (int k = 0; k < PER; k++) { int i = beg + k; if (i < NBUCK) cnt[i] = prefk[k]; }
    __syncthreads();

    // place into LDS in sorted order; precompute global addr per slot
#pragma unroll
    for (int q = 0; q < 16; q++) {
        if (bkt[q] >= 0) {
            int b = bkt[q];
            int pos = atomicAdd(&cnt[b], 1);
            sval[pos] = pay[q];
            saddr[pos] = delta[b] + pos;
        }
    }
    __syncthreads();
    // coalesced-ish write: consecutive sorted slots -> consecutive global addrs within runs
    for (int i = t; i < n; i += 256) pairs[saddr[i]] = sval[i];
}

// ============ mean aggregation: block per bucket, local counting sort + gather ============
__global__ __launch_bounds__(256) void aggregate_kernel(
        const unsigned short* __restrict__ xbf, const unsigned* __restrict__ pairs,
        const int* __restrict__ gcur, unsigned short* __restrict__ aggn) {
    __shared__ int cnt64[64];
    __shared__ int soff[65];
    __shared__ int scur[64];
    __shared__ unsigned short ssrc[CAP];
    int t = threadIdx.x, b = blockIdx.x;
    if (t < 64) cnt64[t] = 0;
    __syncthreads();
    // pass A: count per-seg degree over the 16 sub-regions
    for (int s = 0; s < SUBS; s++) {
        int rbase = b * BUCKCAP + s * SUBCAP;
        int rcnt = gcur[b * SUBS + s] - rbase;
        for (int i = t; i < rcnt; i += 256)
            atomicAdd(&cnt64[pairs[rbase + i] >> 16], 1);
    }
    __syncthreads();
    if (t < 64) {  // wave 0: exclusive scan
        int v = cnt64[t];
        int s = v;
#pragma unroll
        for (int o = 1; o < 64; o <<= 1) {
            int u = __shfl_up(s, o);
            if (t >= o) s += u;
        }
        soff[t + 1] = s;
        if (t == 0) soff[0] = 0;
        scur[t] = s - v;
    }
    __syncthreads();
    // pass B: place srcs per-dst-contiguous
    for (int s = 0; s < SUBS; s++) {
        int rbase = b * BUCKCAP + s * SUBCAP;
        int rcnt = gcur[b * SUBS + s] - rbase;
        for (int i = t; i < rcnt; i += 256) {
            unsigned p = pairs[rbase + i];
            int pos = atomicAdd(&scur[p >> 16], 1);
            ssrc[pos] = (unsigned short)(p & 0xFFFF);
        }
    }
    __syncthreads();
    // gather-reduce: wave per dst, float2/lane, 4-edge ILP
    int wv = t >> 6, lane = t & 63;
    int rowbase = (b < RELSPLIT_B) ? 0 : NPAT;
    int seglim  = (b < RELSPLIT_B) ? NCON : SEGN;
    const unsigned* xw = (const unsigned*)xbf;
    for (int i = 0; i < 16; i++) {
        int d = wv * 16 + i;
        int seg = b * 64 + d;
        if (seg >= seglim) continue;
        int beg = soff[d], end = soff[d + 1];
        float2 A0 = {0.f, 0.f}, A1 = {0.f, 0.f}, A2 = {0.f, 0.f}, A3 = {0.f, 0.f};
        int jj = beg;
        for (; (jj & 3) && jj < end; jj++) {
            unsigned v = xw[(size_t)(rowbase + ssrc[jj]) * 64 + lane];
            A0.x += bf2f_lo(v); A0.y += bf2f_hi(v);
        }
        for (; jj + 3 < end; jj += 4) {
            ushort4 s4 = *(const ushort4*)&ssrc[jj];
            unsigned v0 = xw[(size_t)(rowbase + s4.x) * 64 + lane];
            unsigned v1 = xw[(size_t)(rowbase + s4.y) * 64 + lane];
            unsigned v2 = xw[(size_t)(rowbase + s4.z) * 64 + lane];
            unsigned v3 = xw[(size_t)(rowbase + s4.w) * 64 + lane];
            A0.x += bf2f_lo(v0); A0.y += bf2f_hi(v0);
            A1.x += bf2f_lo(v1); A1.y += bf2f_hi(v1);
            A2.x += bf2f_lo(v2); A2.y += bf2f_hi(v2);
            A3.x += bf2f_lo(v3); A3.y += bf2f_hi(v3);
        }
        for (; jj < end; jj++) {
            unsigned v = xw[(size_t)(rowbase + ssrc[jj]) * 64 + lane];
            A0.x += bf2f_lo(v); A0.y += bf2f_hi(v);
        }
        float inv = 1.0f / (float)max(end - beg, 1);
        ushort2 o;
        o.x = f2bf((A0.x + A1.x + A2.x + A3.x) * inv);
        o.y = f2bf((A0.y + A1.y + A2.y + A3.y) * inv);
        *(ushort2*)&aggn[(size_t)seg * H + 2 * lane] = o;  // zero-deg segs write 0 (required)
    }
}

// ============ proj GEMM (fp32 VALU): Cbf = A1 @ B1 + bias ============
#define BM 128
#define BK 8

struct GemmJob {
    const float* A1;
    const float* B1;
    const float* bias; unsigned short* Cbf;
    int lda1, K1, M;
};

__global__ void gemm_dual_kernel(GemmJob j0, GemmJob j1, int nb0) {
    __shared__ float sA[BK][BM];
    __shared__ float sB[BK][H];
    bool first = (int)blockIdx.x < nb0;
    GemmJob j = first ? j0 : j1;
    int bm = (first ? blockIdx.x : blockIdx.x - nb0) * BM;
    int tid = threadIdx.x;
    int am = tid >> 1;
    int ak = (tid & 1) * 4;
    int bk = tid >> 5;
    int bn = (tid & 31) * 4;
    int ty = tid >> 4;
    int tx = tid & 15;
    float acc[8][8] = {};
    for (int k0 = 0; k0 < j.K1; k0 += BK) {
        int gm = bm + am; if (gm >= j.M) gm = j.M - 1;
        float4 av = *(const float4*)&j.A1[(size_t)gm * j.lda1 + k0 + ak];
        float4 bv = *(const float4*)&j.B1[(size_t)(k0 + bk) * H + bn];
        __syncthreads();
        sA[ak + 0][am] = av.x; sA[ak + 1][am] = av.y;
        sA[ak + 2][am] = av.z; sA[ak + 3][am] = av.w;
        *(float4*)&sB[bk][bn] = bv;
        __syncthreads();
#pragma unroll
        for (int k = 0; k < BK; k++) {
            float a[8], bb[8];
            *(float4*)&a[0] = *(const float4*)&sA[k][ty * 8];
            *(float4*)&a[4] = *(const float4*)&sA[k][ty * 8 + 4];
            *(float4*)&bb[0] = *(const float4*)&sB[k][tx * 4];
            *(float4*)&bb[4] = *(const float4*)&sB[k][64 + tx * 4];
#pragma unroll
            for (int i = 0; i < 8; i++)
#pragma unroll
                for (int jj = 0; jj < 8; jj++)
                    acc[i][jj] += a[i] * bb[jj];
        }
    }
    float bcol[8];
    *(float4*)&bcol[0] = *(const float4*)&j.bias[tx * 4];
    *(float4*)&bcol[4] = *(const float4*)&j.bias[64 + tx * 4];
#pragma unroll
    for (int i = 0; i < 8; i++) {
        int gr = bm + ty * 8 + i;
        if (gr < j.M) {
#pragma unroll
            for (int q = 0; q < 8; q++) {
                float v = acc[i][q] + bcol[q];
                int gc = (q < 4) ? (tx * 4 + q) : (64 + tx * 4 + q - 4);
                j.Cbf[(size_t)gr * H + gc] = f2bf(v);
            }
        }
    }
}

// ============ layer GEMM (bf16 MFMA): C = [A1|A2] @ bf16([B1;B2]) + bias, relu ======
struct MJob {
    const unsigned short* A1;  // [M][H] bf16
    const unsigned short* A2;  // [M][H] bf16
    const float* B1;           // [H][H] fp32 k-major
    const float* B2;
    const float* bias;
    float* C;                  // fp32 or null
    unsigned short* Cbf;       // bf16 or null
    int M;
};

__global__ __launch_bounds__(256) void gemm_mfma_kernel(MJob j0, MJob j1, int nb0) {
    __shared__ unsigned short sA[128][40];   // [row][k] pad 32->40
    __shared__ unsigned short sBT[128][40];  // [col][k]
    bool first = (int)blockIdx.x < nb0;
    MJob J = first ? j0 : j1;
    int bm = (first ? (int)blockIdx.x : (int)blockIdx.x - nb0) * 128;
    int tid = threadIdx.x;
    int wv = tid >> 6, lane = tid & 63;
    int wr = wv >> 1, wc = wv & 1;
    int m16 = lane & 15, kg = lane >> 4;

    f32x4 acc[4][4];
#pragma unroll
    for (int a = 0; a < 4; a++)
#pragma unroll
        for (int c = 0; c < 4; c++) acc[a][c] = (f32x4){0.f, 0.f, 0.f, 0.f};

    int ar = tid >> 1, ah = tid & 1;
    int gmA = bm + ar; if (gmA >= J.M) gmA = J.M - 1;
    int bn = tid & 127, bk0 = tid >> 7;

#pragma unroll
    for (int kt = 0; kt < 8; kt++) {
        int k0 = kt * 32;
        const unsigned short* asrc = (k0 < 128)
            ? (J.A1 + (size_t)gmA * H + k0)
            : (J.A2 + (size_t)gmA * H + (k0 - 128));
        const uint4* a4 = (const uint4*)(asrc + ah * 16);
        uint4 av0 = a4[0], av1 = a4[1];
        const float* bsrc = (k0 < 128) ? (J.B1 + (size_t)k0 * H)
                                       : (J.B2 + (size_t)(k0 - 128) * H);
        float bvals[16];
#pragma unroll
        for (int kk = 0; kk < 16; kk++) bvals[kk] = bsrc[(size_t)(2 * kk + bk0) * H + bn];
        __syncthreads();
        { uint4* d4 = (uint4*)&sA[ar][ah * 16]; d4[0] = av0; d4[1] = av1; }
#pragma unroll
        for (int kk = 0; kk < 16; kk++) sBT[bn][2 * kk + bk0] = f2bf(bvals[kk]);
        __syncthreads();
        bf16x8 af[4], bfg[4];
#pragma unroll
        for (int mt = 0; mt < 4; mt++)
            af[mt] = *(bf16x8*)&sA[wr * 64 + mt * 16 + m16][kg * 8];
#pragma unroll
        for (int nt = 0; nt < 4; nt++)
            bfg[nt] = *(bf16x8*)&sBT[wc * 64 + nt * 16 + m16][kg * 8];
#pragma unroll
        for (int mt = 0; mt < 4; mt++)
#pragma unroll
            for (int nt = 0; nt < 4; nt++)
                acc[mt][nt] = __builtin_amdgcn_mfma_f32_16x16x32_bf16(
                    af[mt], bfg[nt], acc[mt][nt], 0, 0, 0);
    }
    float bv[4];
#pragma unroll
    for (int nt = 0; nt < 4; nt++) bv[nt] = J.bias[wc * 64 + nt * 16 + m16];
#pragma unroll
    for (int mt = 0; mt < 4; mt++) {
        int gr0 = bm + wr * 64 + mt * 16 + kg * 4;
#pragma unroll
        for (int r = 0; r < 4; r++) {
            int gr = gr0 + r;
            if (gr < J.M) {
#pragma unroll
                for (int nt = 0; nt < 4; nt++) {
                    int gc = wc * 64 + nt * 16 + m16;
                    float v = fmaxf(acc[mt][nt][r] + bv[nt], 0.f);
                    if (J.C)   J.C[(size_t)gr * H + gc] = v;
                    if (J.Cbf) J.Cbf[(size_t)gr * H + gc] = f2bf(v);
                }
            }
        }
    }
}

// ============ launch ============

extern "C" void kernel_launch(void* const* d_in, const int* in_sizes, int n_in,
                              void* d_out, int out_size, void* d_ws, size_t ws_size,
                              hipStream_t stream) {
    const float* x_patient = (const float*)d_in[0];
    const float* x_concept = (const float*)d_in[1];
    const float* W_p       = (const float*)d_in[2];
    const float* b_p       = (const float*)d_in[3];
    const float* W_c       = (const float*)d_in[4];
    const float* b_c       = (const float*)d_in[5];
    const float* W_root    = (const float*)d_in[6];
    const float* b_root    = (const float*)d_in[7];
    const float* W_rel     = (const float*)d_in[8];
    const int*   src_pc    = (const int*)d_in[9];
    const int*   dst_pc    = (const int*)d_in[10];
    const int*   src_cp    = (const int*)d_in[11];
    const int*   dst_cp    = (const int*)d_in[12];
    float* out = (float*)d_out;

    char* w = (char*)d_ws;
    unsigned short* xbf  = (unsigned short*)w; w += (size_t)NN * H * 2;     // 17.9 MB
    unsigned short* aggn = (unsigned short*)w; w += (size_t)SEGN * H * 2;   // 17.9 MB
    int* gcur = (int*)w;            w += (size_t)NBUCK * SUBS * 4;          // 70 KB
    unsigned* pairs = (unsigned*)w; w += (size_t)NBUCK * BUCKCAP * 4;       // 22.4 MB

    init_gcur_kernel<<<(NBUCK * SUBS + 255) / 256, 256, 0, stream>>>(gcur);
    binpack_kernel<<<NBB, 256, 0, stream>>>(dst_pc, src_pc, dst_cp, src_cp, gcur, pairs);

    const int PB = (NPAT + BM - 1) / BM;  // 391
    const int CB = (NCON + BM - 1) / BM;  // 157

    // projections -> xbf only
    {
        GemmJob jp = { x_patient, W_p, b_p, xbf, 64, 64, NPAT };
        GemmJob jc = { x_concept, W_c, b_c, xbf + (size_t)NPAT * H, 128, 128, NCON };
        gemm_dual_kernel<<<PB + CB, 256, 0, stream>>>(jp, jc, PB);
    }

    for (int l = 0; l < 2; l++) {
        aggregate_kernel<<<NBUCK, 256, 0, stream>>>(xbf, pairs, gcur, aggn);
        const float* Wroot_l = W_root + (size_t)l * H * H;
        const float* Wrel_l0 = W_rel + (size_t)(l * 2 + 0) * H * H;
        const float* Wrel_l1 = W_rel + (size_t)(l * 2 + 1) * H * H;
        const float* br = b_root + (size_t)l * H;
        float* cp = (l == 1) ? out : nullptr;
        float* cc = (l == 1) ? out + (size_t)NPAT * H : nullptr;
        unsigned short* bp = (l == 0) ? xbf : nullptr;                       // in-place ok
        unsigned short* bc = (l == 0) ? xbf + (size_t)NPAT * H : nullptr;
        MJob jp = { xbf, aggn + (size_t)NCON_AL * H, Wroot_l, Wrel_l1, br,
                    cp, bp, NPAT };
        MJob jc = { xbf + (size_t)NPAT * H, aggn, Wroot_l, Wrel_l0, br,
                    cc, bc, NCON };
        gemm_mfma_kernel<<<PB + CB, 256, 0, stream>>>(jp, jc, PB);
    }
}

// Round 7
// 342.349 us; speedup vs baseline: 9.3454x; 1.1161x over previous
//
#include <hip/hip_runtime.h>
#include <hip/hip_bf16.h>

#define NPAT 50000
#define NCON 20000
#define NN   70000
#define EE   800000
#define H    128

#define NCON_AL  20032                 // concepts padded to 64-alignment
#define SEGN     (NCON_AL + NPAT)      // 70032 segment ids
#define NBUCK    1095                  // ceil(SEGN/64)
#define RELSPLIT_B 313                 // buckets [0,313) = concept dsts (rel0)
#define BUCKCAP  5120                  // pairs capacity per bucket (max fill ~2900)
#define SUBS     16                    // sub-regions per bucket (reservation slots)
#define SUBCAP   (BUCKCAP / SUBS)      // 320 (max fill ~236)
#define BPE      4096                  // edges per binpack block
#define NBB      ((2 * EE + BPE - 1) / BPE)   // 391
#define CAP      4096                  // aggregate LDS edge capacity (max bucket ~2900)

typedef __attribute__((ext_vector_type(8))) short bf16x8;
typedef __attribute__((ext_vector_type(4))) float f32x4;

__device__ inline unsigned short f2bf(float f) {
    unsigned u = __float_as_uint(f);
    unsigned r = (u + 0x7FFFu + ((u >> 16) & 1u)) >> 16;
    return (unsigned short)r;
}
__device__ inline float bf2f_lo(unsigned v) { return __uint_as_float(v << 16); }
__device__ inline float bf2f_hi(unsigned v) { return __uint_as_float(v & 0xFFFF0000u); }

// ============ init: per-(bucket,sub) cursors at static bases ============
__global__ void init_gcur_kernel(int* __restrict__ gcur) {
    int j = blockIdx.x * 256 + threadIdx.x;
    if (j < NBUCK * SUBS) gcur[j] = (j >> 4) * BUCKCAP + (j & (SUBS - 1)) * SUBCAP;
}

// ============ binpack: block-local LDS counting sort by bucket, run-reserve, coalesced write ====
__global__ __launch_bounds__(256) void binpack_kernel(
        const int* __restrict__ dst_pc, const int* __restrict__ src_pc,
        const int* __restrict__ dst_cp, const int* __restrict__ src_cp,
        int* __restrict__ gcur, unsigned* __restrict__ pairs) {
    __shared__ unsigned sval[BPE];       // 16 KB
    __shared__ int saddr[BPE];           // 16 KB
    __shared__ int cnt[NBUCK];           // 4.4 KB (becomes local cursor in place phase)
    __shared__ int delta[NBUCK];         // 4.4 KB
    __shared__ int partial[256];
    int t = threadIdx.x, blk = blockIdx.x;
    int base = blk * BPE;
    int n = min(BPE, 2 * EE - base);

    for (int i = t; i < NBUCK; i += 256) cnt[i] = 0;
    __syncthreads();

    unsigned pay[16];
    int bkt[16];
#pragma unroll
    for (int q = 0; q < 16; q++) {
        int li = q * 256 + t;
        bkt[q] = -1;
        if (li < n) {
            int i = base + li;
            int seg, src;
            if (i < EE) { seg = dst_pc[i];                src = src_pc[i]; }
            else        { seg = NCON_AL + dst_cp[i - EE]; src = src_cp[i - EE]; }
            int b = seg >> 6;
            pay[q] = (unsigned)src | ((unsigned)(seg & 63) << 16);
            bkt[q] = b;
            atomicAdd(&cnt[b], 1);
        }
    }
    __syncthreads();

    const int PER = (NBUCK + 255) / 256;   // 5
    int beg = t * PER;
    int s = 0;
#pragma unroll
    for (int k = 0; k < PER; k++) { int i = beg + k; if (i < NBUCK) s += cnt[i]; }
    partial[t] = s;
    __syncthreads();
    for (int o = 1; o < 256; o <<= 1) {
        int v = (t >= o) ? partial[t - o] : 0;
        __syncthreads();
        partial[t] += v;
        __syncthreads();
    }
    int run = partial[t] - s;
    int sub = blk & (SUBS - 1);
    int prefk[PER];
#pragma unroll
    for (int k = 0; k < PER; k++) {
        int i = beg + k;
        if (i < NBUCK) {
            prefk[k] = run;
            int c = cnt[i];
            if (c > 0) {
                int gb = atomicAdd(&gcur[i * SUBS + sub], c);
                delta[i] = gb - run;
            }
            run += c;
        }
    }
    __syncthreads();
#pragma unroll
    for (int k = 0; k < PER; k++) { int i = beg + k; if (i < NBUCK) cnt[i] = prefk[k]; }
    __syncthreads();

#pragma unroll
    for (int q = 0; q < 16; q++) {
        if (bkt[q] >= 0) {
            int b = bkt[q];
            int pos = atomicAdd(&cnt[b], 1);
            sval[pos] = pay[q];
            saddr[pos] = delta[b] + pos;
        }
    }
    __syncthreads();
    for (int i = t; i < n; i += 256) pairs[saddr[i]] = sval[i];
}

// ============ mean aggregation: block per bucket, 512 threads (8 waves x 8 segs) ============
__global__ __launch_bounds__(512) void aggregate_kernel(
        const unsigned short* __restrict__ xbf, const unsigned* __restrict__ pairs,
        const int* __restrict__ gcur, unsigned short* __restrict__ aggn) {
    __shared__ int cnt64[64];
    __shared__ int soff[65];
    __shared__ int scur[64];
    __shared__ unsigned short ssrc[CAP];
    int t = threadIdx.x, b = blockIdx.x;
    if (t < 64) cnt64[t] = 0;
    __syncthreads();
    // pass A: count per-seg degree over the 16 sub-regions
    for (int s = 0; s < SUBS; s++) {
        int rbase = b * BUCKCAP + s * SUBCAP;
        int rcnt = gcur[b * SUBS + s] - rbase;
        for (int i = t; i < rcnt; i += 512)
            atomicAdd(&cnt64[pairs[rbase + i] >> 16], 1);
    }
    __syncthreads();
    if (t < 64) {  // wave 0: exclusive scan
        int v = cnt64[t];
        int s = v;
#pragma unroll
        for (int o = 1; o < 64; o <<= 1) {
            int u = __shfl_up(s, o);
            if (t >= o) s += u;
        }
        soff[t + 1] = s;
        if (t == 0) soff[0] = 0;
        scur[t] = s - v;
    }
    __syncthreads();
    // pass B: place srcs per-dst-contiguous
    for (int s = 0; s < SUBS; s++) {
        int rbase = b * BUCKCAP + s * SUBCAP;
        int rcnt = gcur[b * SUBS + s] - rbase;
        for (int i = t; i < rcnt; i += 512) {
            unsigned p = pairs[rbase + i];
            int pos = atomicAdd(&scur[p >> 16], 1);
            ssrc[pos] = (unsigned short)(p & 0xFFFF);
        }
    }
    __syncthreads();
    // gather-reduce: 8 waves, each reduces 8 segs; float2/lane, 4-edge ILP
    int wv = t >> 6, lane = t & 63;
    int rowbase = (b < RELSPLIT_B) ? 0 : NPAT;
    int seglim  = (b < RELSPLIT_B) ? NCON : SEGN;
    const unsigned* xw = (const unsigned*)xbf;
    for (int i = 0; i < 8; i++) {
        int d = wv * 8 + i;
        int seg = b * 64 + d;
        if (seg >= seglim) continue;
        int beg = soff[d], end = soff[d + 1];
        float2 A0 = {0.f, 0.f}, A1 = {0.f, 0.f}, A2 = {0.f, 0.f}, A3 = {0.f, 0.f};
        int jj = beg;
        for (; (jj & 3) && jj < end; jj++) {
            unsigned v = xw[(size_t)(rowbase + ssrc[jj]) * 64 + lane];
            A0.x += bf2f_lo(v); A0.y += bf2f_hi(v);
        }
        for (; jj + 3 < end; jj += 4) {
            ushort4 s4 = *(const ushort4*)&ssrc[jj];
            unsigned v0 = xw[(size_t)(rowbase + s4.x) * 64 + lane];
            unsigned v1 = xw[(size_t)(rowbase + s4.y) * 64 + lane];
            unsigned v2 = xw[(size_t)(rowbase + s4.z) * 64 + lane];
            unsigned v3 = xw[(size_t)(rowbase + s4.w) * 64 + lane];
            A0.x += bf2f_lo(v0); A0.y += bf2f_hi(v0);
            A1.x += bf2f_lo(v1); A1.y += bf2f_hi(v1);
            A2.x += bf2f_lo(v2); A2.y += bf2f_hi(v2);
            A3.x += bf2f_lo(v3); A3.y += bf2f_hi(v3);
        }
        for (; jj < end; jj++) {
            unsigned v = xw[(size_t)(rowbase + ssrc[jj]) * 64 + lane];
            A0.x += bf2f_lo(v); A0.y += bf2f_hi(v);
        }
        float inv = 1.0f / (float)max(end - beg, 1);
        ushort2 o;
        o.x = f2bf((A0.x + A1.x + A2.x + A3.x) * inv);
        o.y = f2bf((A0.y + A1.y + A2.y + A3.y) * inv);
        *(ushort2*)&aggn[(size_t)seg * H + 2 * lane] = o;  // zero-deg segs write 0 (required)
    }
}

// ============ proj GEMM (fp32 VALU): Cbf = A1 @ B1 + bias ============
#define BM 128
#define BK 8

struct GemmJob {
    const float* A1;
    const float* B1;
    const float* bias; unsigned short* Cbf;
    int lda1, K1, M;
};

__global__ void gemm_dual_kernel(GemmJob j0, GemmJob j1, int nb0) {
    __shared__ float sA[BK][BM];
    __shared__ float sB[BK][H];
    bool first = (int)blockIdx.x < nb0;
    GemmJob j = first ? j0 : j1;
    int bm = (first ? blockIdx.x : blockIdx.x - nb0) * BM;
    int tid = threadIdx.x;
    int am = tid >> 1;
    int ak = (tid & 1) * 4;
    int bk = tid >> 5;
    int bn = (tid & 31) * 4;
    int ty = tid >> 4;
    int tx = tid & 15;
    float acc[8][8] = {};
    for (int k0 = 0; k0 < j.K1; k0 += BK) {
        int gm = bm + am; if (gm >= j.M) gm = j.M - 1;
        float4 av = *(const float4*)&j.A1[(size_t)gm * j.lda1 + k0 + ak];
        float4 bv = *(const float4*)&j.B1[(size_t)(k0 + bk) * H + bn];
        __syncthreads();
        sA[ak + 0][am] = av.x; sA[ak + 1][am] = av.y;
        sA[ak + 2][am] = av.z; sA[ak + 3][am] = av.w;
        *(float4*)&sB[bk][bn] = bv;
        __syncthreads();
#pragma unroll
        for (int k = 0; k < BK; k++) {
            float a[8], bb[8];
            *(float4*)&a[0] = *(const float4*)&sA[k][ty * 8];
            *(float4*)&a[4] = *(const float4*)&sA[k][ty * 8 + 4];
            *(float4*)&bb[0] = *(const float4*)&sB[k][tx * 4];
            *(float4*)&bb[4] = *(const float4*)&sB[k][64 + tx * 4];
#pragma unroll
            for (int i = 0; i < 8; i++)
#pragma unroll
                for (int jj = 0; jj < 8; jj++)
                    acc[i][jj] += a[i] * bb[jj];
        }
    }
    float bcol[8];
    *(float4*)&bcol[0] = *(const float4*)&j.bias[tx * 4];
    *(float4*)&bcol[4] = *(const float4*)&j.bias[64 + tx * 4];
#pragma unroll
    for (int i = 0; i < 8; i++) {
        int gr = bm + ty * 8 + i;
        if (gr < j.M) {
#pragma unroll
            for (int q = 0; q < 8; q++) {
                float v = acc[i][q] + bcol[q];
                int gc = (q < 4) ? (tx * 4 + q) : (64 + tx * 4 + q - 4);
                j.Cbf[(size_t)gr * H + gc] = f2bf(v);
            }
        }
    }
}

// ============ layer GEMM (bf16 MFMA): C = [A1|A2] @ bf16([B1;B2]) + bias, relu ======
struct MJob {
    const unsigned short* A1;  // [M][H] bf16
    const unsigned short* A2;  // [M][H] bf16
    const float* B1;           // [H][H] fp32 k-major
    const float* B2;
    const float* bias;
    float* C;                  // fp32 or null
    unsigned short* Cbf;       // bf16 or null
    int M;
};

__global__ __launch_bounds__(256) void gemm_mfma_kernel(MJob j0, MJob j1, int nb0) {
    __shared__ unsigned short sA[128][40];   // [row][k] pad 32->40
    __shared__ unsigned short sBT[128][40];  // [col][k]
    bool first = (int)blockIdx.x < nb0;
    MJob J = first ? j0 : j1;
    int bm = (first ? (int)blockIdx.x : (int)blockIdx.x - nb0) * 128;
    int tid = threadIdx.x;
    int wv = tid >> 6, lane = tid & 63;
    int wr = wv >> 1, wc = wv & 1;
    int m16 = lane & 15, kg = lane >> 4;

    f32x4 acc[4][4];
#pragma unroll
    for (int a = 0; a < 4; a++)
#pragma unroll
        for (int c = 0; c < 4; c++) acc[a][c] = (f32x4){0.f, 0.f, 0.f, 0.f};

    int ar = tid >> 1, ah = tid & 1;
    int gmA = bm + ar; if (gmA >= J.M) gmA = J.M - 1;
    int bn = tid & 127, bk0 = tid >> 7;

#pragma unroll
    for (int kt = 0; kt < 8; kt++) {
        int k0 = kt * 32;
        const unsigned short* asrc = (k0 < 128)
            ? (J.A1 + (size_t)gmA * H + k0)
            : (J.A2 + (size_t)gmA * H + (k0 - 128));
        const uint4* a4 = (const uint4*)(asrc + ah * 16);
        uint4 av0 = a4[0], av1 = a4[1];
        const float* bsrc = (k0 < 128) ? (J.B1 + (size_t)k0 * H)
                                       : (J.B2 + (size_t)(k0 - 128) * H);
        float bvals[16];
#pragma unroll
        for (int kk = 0; kk < 16; kk++) bvals[kk] = bsrc[(size_t)(2 * kk + bk0) * H + bn];
        __syncthreads();
        { uint4* d4 = (uint4*)&sA[ar][ah * 16]; d4[0] = av0; d4[1] = av1; }
#pragma unroll
        for (int kk = 0; kk < 16; kk++) sBT[bn][2 * kk + bk0] = f2bf(bvals[kk]);
        __syncthreads();
        bf16x8 af[4], bfg[4];
#pragma unroll
        for (int mt = 0; mt < 4; mt++)
            af[mt] = *(bf16x8*)&sA[wr * 64 + mt * 16 + m16][kg * 8];
#pragma unroll
        for (int nt = 0; nt < 4; nt++)
            bfg[nt] = *(bf16x8*)&sBT[wc * 64 + nt * 16 + m16][kg * 8];
#pragma unroll
        for (int mt = 0; mt < 4; mt++)
#pragma unroll
            for (int nt = 0; nt < 4; nt++)
                acc[mt][nt] = __builtin_amdgcn_mfma_f32_16x16x32_bf16(
                    af[mt], bfg[nt], acc[mt][nt], 0, 0, 0);
    }
    float bv[4];
#pragma unroll
    for (int nt = 0; nt < 4; nt++) bv[nt] = J.bias[wc * 64 + nt * 16 + m16];
#pragma unroll
    for (int mt = 0; mt < 4; mt++) {
        int gr0 = bm + wr * 64 + mt * 16 + kg * 4;
#pragma unroll
        for (int r = 0; r < 4; r++) {
            int gr = gr0 + r;
            if (gr < J.M) {
#pragma unroll
                for (int nt = 0; nt < 4; nt++) {
                    int gc = wc * 64 + nt * 16 + m16;
                    float v = fmaxf(acc[mt][nt][r] + bv[nt], 0.f);
                    if (J.C)   J.C[(size_t)gr * H + gc] = v;
                    if (J.Cbf) J.Cbf[(size_t)gr * H + gc] = f2bf(v);
                }
            }
        }
    }
}

// ============ launch ============

extern "C" void kernel_launch(void* const* d_in, const int* in_sizes, int n_in,
                              void* d_out, int out_size, void* d_ws, size_t ws_size,
                              hipStream_t stream) {
    const float* x_patient = (const float*)d_in[0];
    const float* x_concept = (const float*)d_in[1];
    const float* W_p       = (const float*)d_in[2];
    const float* b_p       = (const float*)d_in[3];
    const float* W_c       = (const float*)d_in[4];
    const float* b_c       = (const float*)d_in[5];
    const float* W_root    = (const float*)d_in[6];
    const float* b_root    = (const float*)d_in[7];
    const float* W_rel     = (const float*)d_in[8];
    const int*   src_pc    = (const int*)d_in[9];
    const int*   dst_pc    = (const int*)d_in[10];
    const int*   src_cp    = (const int*)d_in[11];
    const int*   dst_cp    = (const int*)d_in[12];
    float* out = (float*)d_out;

    char* w = (char*)d_ws;
    unsigned short* xbf  = (unsigned short*)w; w += (size_t)NN * H * 2;     // 17.9 MB
    unsigned short* aggn = (unsigned short*)w; w += (size_t)SEGN * H * 2;   // 17.9 MB
    int* gcur = (int*)w;            w += (size_t)NBUCK * SUBS * 4;          // 70 KB
    unsigned* pairs = (unsigned*)w; w += (size_t)NBUCK * BUCKCAP * 4;       // 22.4 MB

    init_gcur_kernel<<<(NBUCK * SUBS + 255) / 256, 256, 0, stream>>>(gcur);
    binpack_kernel<<<NBB, 256, 0, stream>>>(dst_pc, src_pc, dst_cp, src_cp, gcur, pairs);

    const int PB = (NPAT + BM - 1) / BM;  // 391
    const int CB = (NCON + BM - 1) / BM;  // 157

    // projections -> xbf only
    {
        GemmJob jp = { x_patient, W_p, b_p, xbf, 64, 64, NPAT };
        GemmJob jc = { x_concept, W_c, b_c, xbf + (size_t)NPAT * H, 128, 128, NCON };
        gemm_dual_kernel<<<PB + CB, 256, 0, stream>>>(jp, jc, PB);
    }

    for (int l = 0; l < 2; l++) {
        aggregate_kernel<<<NBUCK, 512, 0, stream>>>(xbf, pairs, gcur, aggn);
        const float* Wroot_l = W_root + (size_t)l * H * H;
        const float* Wrel_l0 = W_rel + (size_t)(l * 2 + 0) * H * H;
        const float* Wrel_l1 = W_rel + (size_t)(l * 2 + 1) * H * H;
        const float* br = b_root + (size_t)l * H;
        float* cp = (l == 1) ? out : nullptr;
        float* cc = (l == 1) ? out + (size_t)NPAT * H : nullptr;
        unsigned short* bp = (l == 0) ? xbf : nullptr;                       // in-place ok
        unsigned short* bc = (l == 0) ? xbf + (size_t)NPAT * H : nullptr;
        MJob jp = { xbf, aggn + (size_t)NCON_AL * H, Wroot_l, Wrel_l1, br,
                    cp, bp, NPAT };
        MJob jc = { xbf + (size_t)NPAT * H, aggn, Wroot_l, Wrel_l0, br,
                    cc, bc, NCON };
        gemm_mfma_kernel<<<PB + CB, 256, 0, stream>>>(jp, jc, PB);
    }
}

// Round 8
// 331.814 us; speedup vs baseline: 9.6422x; 1.0317x over previous
//
#include <hip/hip_runtime.h>
#include <hip/hip_bf16.h>

#define NPAT 50000
#define NCON 20000
#define NN   70000
#define EE   800000
#define H    128

#define NCON_AL  20032                 // concepts padded to 64-alignment
#define SEGN     (NCON_AL + NPAT)      // 70032 segment ids
#define NBUCK    1095                  // ceil(SEGN/64)
#define RELSPLIT_B 313                 // buckets [0,313) = concept dsts (rel0)
#define BUCKCAP  5120                  // pairs capacity per bucket (max fill ~2900)
#define SUBS     16                    // sub-regions per bucket (reservation slots)
#define SUBCAP   (BUCKCAP / SUBS)      // 320 (max fill ~236)
#define BPE      4096                  // edges per binpack block
#define NBB      ((2 * EE + BPE - 1) / BPE)   // 391
#define CAP      4096                  // aggregate LDS edge capacity (max bucket ~2900)

typedef __attribute__((ext_vector_type(8))) short bf16x8;
typedef __attribute__((ext_vector_type(4))) float f32x4;

__device__ inline unsigned short f2bf(float f) {
    unsigned u = __float_as_uint(f);
    unsigned r = (u + 0x7FFFu + ((u >> 16) & 1u)) >> 16;
    return (unsigned short)r;
}
__device__ inline float bf2f_lo(unsigned v) { return __uint_as_float(v << 16); }
__device__ inline float bf2f_hi(unsigned v) { return __uint_as_float(v & 0xFFFF0000u); }

// ============ init: per-(bucket,sub) cursors at static bases ============
__global__ void init_gcur_kernel(int* __restrict__ gcur) {
    int j = blockIdx.x * 256 + threadIdx.x;
    if (j < NBUCK * SUBS) gcur[j] = (j >> 4) * BUCKCAP + (j & (SUBS - 1)) * SUBCAP;
}

// ============ binpack: 512 thr, LDS counting sort by bucket, run-reserve, write ====
__global__ __launch_bounds__(512) void binpack_kernel(
        const int* __restrict__ dst_pc, const int* __restrict__ src_pc,
        const int* __restrict__ dst_cp, const int* __restrict__ src_cp,
        int* __restrict__ gcur, unsigned* __restrict__ pairs) {
    __shared__ unsigned sval[BPE];           // 16 KB
    __shared__ unsigned short sbkt[BPE];     // 8 KB (bucket id per sorted slot)
    __shared__ int cnt[NBUCK];               // 4.4 KB (then local cursor)
    __shared__ int delta[NBUCK];             // 4.4 KB
    __shared__ int partial[512];
    int t = threadIdx.x, blk = blockIdx.x;
    int base = blk * BPE;
    int n = min(BPE, 2 * EE - base);

    for (int i = t; i < NBUCK; i += 512) cnt[i] = 0;
    __syncthreads();

    unsigned pay[8];
    int bkt[8];
#pragma unroll
    for (int q = 0; q < 8; q++) {
        int li = q * 512 + t;
        bkt[q] = -1;
        if (li < n) {
            int i = base + li;
            int seg, src;
            if (i < EE) { seg = dst_pc[i];                src = src_pc[i]; }
            else        { seg = NCON_AL + dst_cp[i - EE]; src = src_cp[i - EE]; }
            int b = seg >> 6;
            pay[q] = (unsigned)src | ((unsigned)(seg & 63) << 16);
            bkt[q] = b;
            atomicAdd(&cnt[b], 1);
        }
    }
    __syncthreads();

    const int PER = (NBUCK + 511) / 512;   // 3
    int beg = t * PER;
    int s = 0;
#pragma unroll
    for (int k = 0; k < PER; k++) { int i = beg + k; if (i < NBUCK) s += cnt[i]; }
    partial[t] = s;
    __syncthreads();
    for (int o = 1; o < 512; o <<= 1) {
        int v = (t >= o) ? partial[t - o] : 0;
        __syncthreads();
        partial[t] += v;
        __syncthreads();
    }
    int run = partial[t] - s;
    int sub = blk & (SUBS - 1);
    int prefk[PER];
#pragma unroll
    for (int k = 0; k < PER; k++) {
        int i = beg + k;
        if (i < NBUCK) {
            prefk[k] = run;
            int c = cnt[i];
            if (c > 0) {
                int gb = atomicAdd(&gcur[i * SUBS + sub], c);
                delta[i] = gb - run;
            }
            run += c;
        }
    }
    __syncthreads();
#pragma unroll
    for (int k = 0; k < PER; k++) { int i = beg + k; if (i < NBUCK) cnt[i] = prefk[k]; }
    __syncthreads();

#pragma unroll
    for (int q = 0; q < 8; q++) {
        if (bkt[q] >= 0) {
            int b = bkt[q];
            int pos = atomicAdd(&cnt[b], 1);
            sval[pos] = pay[q];
            sbkt[pos] = (unsigned short)b;
        }
    }
    __syncthreads();
    for (int i = t; i < n; i += 512)
        pairs[delta[sbkt[i]] + i] = sval[i];
}

// ============ mean aggregation: block per bucket, 512 thr; paired 8B/lane gather ============
__global__ __launch_bounds__(512) void aggregate_kernel(
        const unsigned short* __restrict__ xbf, const unsigned* __restrict__ pairs,
        const int* __restrict__ gcur, unsigned short* __restrict__ aggn) {
    __shared__ int cnt64[64];
    __shared__ int soff[65];
    __shared__ int scur[64];
    __shared__ unsigned short ssrc[CAP];
    int t = threadIdx.x, b = blockIdx.x;
    if (t < 64) cnt64[t] = 0;
    __syncthreads();
    // pass A: count per-seg degree over the 16 sub-regions
    for (int s = 0; s < SUBS; s++) {
        int rbase = b * BUCKCAP + s * SUBCAP;
        int rcnt = gcur[b * SUBS + s] - rbase;
        for (int i = t; i < rcnt; i += 512)
            atomicAdd(&cnt64[pairs[rbase + i] >> 16], 1);
    }
    __syncthreads();
    if (t < 64) {  // wave 0: exclusive scan
        int v = cnt64[t];
        int s = v;
#pragma unroll
        for (int o = 1; o < 64; o <<= 1) {
            int u = __shfl_up(s, o);
            if (t >= o) s += u;
        }
        soff[t + 1] = s;
        if (t == 0) soff[0] = 0;
        scur[t] = s - v;
    }
    __syncthreads();
    // pass B: place srcs per-dst-contiguous
    for (int s = 0; s < SUBS; s++) {
        int rbase = b * BUCKCAP + s * SUBCAP;
        int rcnt = gcur[b * SUBS + s] - rbase;
        for (int i = t; i < rcnt; i += 512) {
            unsigned p = pairs[rbase + i];
            int pos = atomicAdd(&scur[p >> 16], 1);
            ssrc[pos] = (unsigned short)(p & 0xFFFF);
        }
    }
    __syncthreads();
    // gather: 8 waves x 8 segs; wave processes 2 edges at once (half h, 8B/lane)
    int wv = t >> 6, lane = t & 63;
    int h = lane >> 5, cl = lane & 31;
    int rowbase = (b < RELSPLIT_B) ? 0 : NPAT;
    int seglim  = (b < RELSPLIT_B) ? NCON : SEGN;
    const unsigned* xw = (const unsigned*)xbf;   // 64 uints/row; lane covers uints 2cl,2cl+1
    for (int i = 0; i < 8; i++) {
        int d = wv * 8 + i;
        int seg = b * 64 + d;
        if (seg >= seglim) continue;
        int beg = soff[d], end = soff[d + 1];
        float4 a0 = {0.f, 0.f, 0.f, 0.f}, a1 = {0.f, 0.f, 0.f, 0.f};
        int j = beg;
        if ((end - beg) & 1) {  // odd tail first: half 0 only
            int s0 = ssrc[j];
            uint2 v = *(const uint2*)&xw[(size_t)(rowbase + s0) * 64 + 2 * cl];
            if (h == 0) {
                a0.x += bf2f_lo(v.x); a0.y += bf2f_hi(v.x);
                a0.z += bf2f_lo(v.y); a0.w += bf2f_hi(v.y);
            }
            j++;
        }
        for (; j + 3 < end; j += 4) {  // 4 edges via 2 paired loads
            int sA = ssrc[j + h];
            int sB = ssrc[j + 2 + h];
            uint2 vA = *(const uint2*)&xw[(size_t)(rowbase + sA) * 64 + 2 * cl];
            uint2 vB = *(const uint2*)&xw[(size_t)(rowbase + sB) * 64 + 2 * cl];
            a0.x += bf2f_lo(vA.x); a0.y += bf2f_hi(vA.x);
            a0.z += bf2f_lo(vA.y); a0.w += bf2f_hi(vA.y);
            a1.x += bf2f_lo(vB.x); a1.y += bf2f_hi(vB.x);
            a1.z += bf2f_lo(vB.y); a1.w += bf2f_hi(vB.y);
        }
        if (j + 1 < end) {  // exactly 2 left
            int sA = ssrc[j + h];
            uint2 vA = *(const uint2*)&xw[(size_t)(rowbase + sA) * 64 + 2 * cl];
            a0.x += bf2f_lo(vA.x); a0.y += bf2f_hi(vA.x);
            a0.z += bf2f_lo(vA.y); a0.w += bf2f_hi(vA.y);
        }
        a0.x += a1.x; a0.y += a1.y; a0.z += a1.z; a0.w += a1.w;
        // cross-half combine
        a0.x += __shfl_xor(a0.x, 32);
        a0.y += __shfl_xor(a0.y, 32);
        a0.z += __shfl_xor(a0.z, 32);
        a0.w += __shfl_xor(a0.w, 32);
        if (h == 0) {
            float inv = 1.0f / (float)max(end - beg, 1);
            ushort4 o;
            o.x = f2bf(a0.x * inv); o.y = f2bf(a0.y * inv);
            o.z = f2bf(a0.z * inv); o.w = f2bf(a0.w * inv);
            *(ushort4*)&aggn[(size_t)seg * H + 4 * cl] = o;  // zero-deg segs write 0 (required)
        }
    }
}

// ============ proj GEMM (fp32 VALU): Cbf = A1 @ B1 + bias ============
#define BM 128
#define BK 8

struct GemmJob {
    const float* A1;
    const float* B1;
    const float* bias; unsigned short* Cbf;
    int lda1, K1, M;
};

__global__ void gemm_dual_kernel(GemmJob j0, GemmJob j1, int nb0) {
    __shared__ float sA[BK][BM];
    __shared__ float sB[BK][H];
    bool first = (int)blockIdx.x < nb0;
    GemmJob j = first ? j0 : j1;
    int bm = (first ? blockIdx.x : blockIdx.x - nb0) * BM;
    int tid = threadIdx.x;
    int am = tid >> 1;
    int ak = (tid & 1) * 4;
    int bk = tid >> 5;
    int bn = (tid & 31) * 4;
    int ty = tid >> 4;
    int tx = tid & 15;
    float acc[8][8] = {};
    for (int k0 = 0; k0 < j.K1; k0 += BK) {
        int gm = bm + am; if (gm >= j.M) gm = j.M - 1;
        float4 av = *(const float4*)&j.A1[(size_t)gm * j.lda1 + k0 + ak];
        float4 bv = *(const float4*)&j.B1[(size_t)(k0 + bk) * H + bn];
        __syncthreads();
        sA[ak + 0][am] = av.x; sA[ak + 1][am] = av.y;
        sA[ak + 2][am] = av.z; sA[ak + 3][am] = av.w;
        *(float4*)&sB[bk][bn] = bv;
        __syncthreads();
#pragma unroll
        for (int k = 0; k < BK; k++) {
            float a[8], bb[8];
            *(float4*)&a[0] = *(const float4*)&sA[k][ty * 8];
            *(float4*)&a[4] = *(const float4*)&sA[k][ty * 8 + 4];
            *(float4*)&bb[0] = *(const float4*)&sB[k][tx * 4];
            *(float4*)&bb[4] = *(const float4*)&sB[k][64 + tx * 4];
#pragma unroll
            for (int i = 0; i < 8; i++)
#pragma unroll
                for (int jj = 0; jj < 8; jj++)
                    acc[i][jj] += a[i] * bb[jj];
        }
    }
    float bcol[8];
    *(float4*)&bcol[0] = *(const float4*)&j.bias[tx * 4];
    *(float4*)&bcol[4] = *(const float4*)&j.bias[64 + tx * 4];
#pragma unroll
    for (int i = 0; i < 8; i++) {
        int gr = bm + ty * 8 + i;
        if (gr < j.M) {
#pragma unroll
            for (int q = 0; q < 8; q++) {
                float v = acc[i][q] + bcol[q];
                int gc = (q < 4) ? (tx * 4 + q) : (64 + tx * 4 + q - 4);
                j.Cbf[(size_t)gr * H + gc] = f2bf(v);
            }
        }
    }
}

// ============ layer GEMM (bf16 MFMA): C = [A1|A2] @ bf16([B1;B2]) + bias, relu ======
struct MJob {
    const unsigned short* A1;  // [M][H] bf16
    const unsigned short* A2;  // [M][H] bf16
    const float* B1;           // [H][H] fp32 k-major
    const float* B2;
    const float* bias;
    float* C;                  // fp32 or null
    unsigned short* Cbf;       // bf16 or null
    int M;
};

__global__ __launch_bounds__(256) void gemm_mfma_kernel(MJob j0, MJob j1, int nb0) {
    __shared__ unsigned short sA[128][40];   // [row][k] pad 32->40
    __shared__ unsigned short sBT[128][40];  // [col][k]
    bool first = (int)blockIdx.x < nb0;
    MJob J = first ? j0 : j1;
    int bm = (first ? (int)blockIdx.x : (int)blockIdx.x - nb0) * 128;
    int tid = threadIdx.x;
    int wv = tid >> 6, lane = tid & 63;
    int wr = wv >> 1, wc = wv & 1;
    int m16 = lane & 15, kg = lane >> 4;

    f32x4 acc[4][4];
#pragma unroll
    for (int a = 0; a < 4; a++)
#pragma unroll
        for (int c = 0; c < 4; c++) acc[a][c] = (f32x4){0.f, 0.f, 0.f, 0.f};

    int ar = tid >> 1, ah = tid & 1;
    int gmA = bm + ar; if (gmA >= J.M) gmA = J.M - 1;
    int bn = tid & 127, bk0 = tid >> 7;

#pragma unroll
    for (int kt = 0; kt < 8; kt++) {
        int k0 = kt * 32;
        const unsigned short* asrc = (k0 < 128)
            ? (J.A1 + (size_t)gmA * H + k0)
            : (J.A2 + (size_t)gmA * H + (k0 - 128));
        const uint4* a4 = (const uint4*)(asrc + ah * 16);
        uint4 av0 = a4[0], av1 = a4[1];
        const float* bsrc = (k0 < 128) ? (J.B1 + (size_t)k0 * H)
                                       : (J.B2 + (size_t)(k0 - 128) * H);
        float bvals[16];
#pragma unroll
        for (int kk = 0; kk < 16; kk++) bvals[kk] = bsrc[(size_t)(2 * kk + bk0) * H + bn];
        __syncthreads();
        { uint4* d4 = (uint4*)&sA[ar][ah * 16]; d4[0] = av0; d4[1] = av1; }
#pragma unroll
        for (int kk = 0; kk < 16; kk++) sBT[bn][2 * kk + bk0] = f2bf(bvals[kk]);
        __syncthreads();
        bf16x8 af[4], bfg[4];
#pragma unroll
        for (int mt = 0; mt < 4; mt++)
            af[mt] = *(bf16x8*)&sA[wr * 64 + mt * 16 + m16][kg * 8];
#pragma unroll
        for (int nt = 0; nt < 4; nt++)
            bfg[nt] = *(bf16x8*)&sBT[wc * 64 + nt * 16 + m16][kg * 8];
#pragma unroll
        for (int mt = 0; mt < 4; mt++)
#pragma unroll
            for (int nt = 0; nt < 4; nt++)
                acc[mt][nt] = __builtin_amdgcn_mfma_f32_16x16x32_bf16(
                    af[mt], bfg[nt], acc[mt][nt], 0, 0, 0);
    }
    float bv[4];
#pragma unroll
    for (int nt = 0; nt < 4; nt++) bv[nt] = J.bias[wc * 64 + nt * 16 + m16];
#pragma unroll
    for (int mt = 0; mt < 4; mt++) {
        int gr0 = bm + wr * 64 + mt * 16 + kg * 4;
#pragma unroll
        for (int r = 0; r < 4; r++) {
            int gr = gr0 + r;
            if (gr < J.M) {
#pragma unroll
                for (int nt = 0; nt < 4; nt++) {
                    int gc = wc * 64 + nt * 16 + m16;
                    float v = fmaxf(acc[mt][nt][r] + bv[nt], 0.f);
                    if (J.C)   J.C[(size_t)gr * H + gc] = v;
                    if (J.Cbf) J.Cbf[(size_t)gr * H + gc] = f2bf(v);
                }
            }
        }
    }
}

// ============ launch ============

extern "C" void kernel_launch(void* const* d_in, const int* in_sizes, int n_in,
                              void* d_out, int out_size, void* d_ws, size_t ws_size,
                              hipStream_t stream) {
    const float* x_patient = (const float*)d_in[0];
    const float* x_concept = (const float*)d_in[1];
    const float* W_p       = (const float*)d_in[2];
    const float* b_p       = (const float*)d_in[3];
    const float* W_c       = (const float*)d_in[4];
    const float* b_c       = (const float*)d_in[5];
    const float* W_root    = (const float*)d_in[6];
    const float* b_root    = (const float*)d_in[7];
    const float* W_rel     = (const float*)d_in[8];
    const int*   src_pc    = (const int*)d_in[9];
    const int*   dst_pc    = (const int*)d_in[10];
    const int*   src_cp    = (const int*)d_in[11];
    const int*   dst_cp    = (const int*)d_in[12];
    float* out = (float*)d_out;

    char* w = (char*)d_ws;
    unsigned short* xbf  = (unsigned short*)w; w += (size_t)NN * H * 2;     // 17.9 MB
    unsigned short* aggn = (unsigned short*)w; w += (size_t)SEGN * H * 2;   // 17.9 MB
    int* gcur = (int*)w;            w += (size_t)NBUCK * SUBS * 4;          // 70 KB
    unsigned* pairs = (unsigned*)w; w += (size_t)NBUCK * BUCKCAP * 4;       // 22.4 MB

    init_gcur_kernel<<<(NBUCK * SUBS + 255) / 256, 256, 0, stream>>>(gcur);
    binpack_kernel<<<NBB, 512, 0, stream>>>(dst_pc, src_pc, dst_cp, src_cp, gcur, pairs);

    const int PB = (NPAT + BM - 1) / BM;  // 391
    const int CB = (NCON + BM - 1) / BM;  // 157

    // projections -> xbf only
    {
        GemmJob jp = { x_patient, W_p, b_p, xbf, 64, 64, NPAT };
        GemmJob jc = { x_concept, W_c, b_c, xbf + (size_t)NPAT * H, 128, 128, NCON };
        gemm_dual_kernel<<<PB + CB, 256, 0, stream>>>(jp, jc, PB);
    }

    for (int l = 0; l < 2; l++) {
        aggregate_kernel<<<NBUCK, 512, 0, stream>>>(xbf, pairs, gcur, aggn);
        const float* Wroot_l = W_root + (size_t)l * H * H;
        const float* Wrel_l0 = W_rel + (size_t)(l * 2 + 0) * H * H;
        const float* Wrel_l1 = W_rel + (size_t)(l * 2 + 1) * H * H;
        const float* br = b_root + (size_t)l * H;
        float* cp = (l == 1) ? out : nullptr;
        float* cc = (l == 1) ? out + (size_t)NPAT * H : nullptr;
        unsigned short* bp = (l == 0) ? xbf : nullptr;                       // in-place ok
        unsigned short* bc = (l == 0) ? xbf + (size_t)NPAT * H : nullptr;
        MJob jp = { xbf, aggn + (size_t)NCON_AL * H, Wroot_l, Wrel_l1, br,
                    cp, bp, NPAT };
        MJob jc = { xbf + (size_t)NPAT * H, aggn, Wroot_l, Wrel_l0, br,
                    cc, bc, NCON };
        gemm_mfma_kernel<<<PB + CB, 256, 0, stream>>>(jp, jc, PB);
    }
}